// Round 9
// baseline (604.910 us; speedup 1.0000x reference)
//
#include <hip/hip_runtime.h>
#include <stdint.h>
#include <stdio.h>

#define S_  2048
#define B_  4
#define D_  256
#define NH_ 4
#define K_  1024
#define FF_ 1024
#define M_  (S_*B_)      // 8192 rows (s,b)
#define HB_ (NH_*B_)     // 16 (h,b) pairs

// bf16 LDS tile row stride (shorts): 128 data + 8 pad (272 B rows).
#define LDSROW 136
// fp8 LDS tile row stride (bytes): 128 data + 16 pad, 16B-aligned.
#define PROW 144

typedef float  f32x4  __attribute__((ext_vector_type(4)));
typedef float  f32x2  __attribute__((ext_vector_type(2)));
typedef __bf16 bf16x8 __attribute__((ext_vector_type(8)));

__device__ __forceinline__ float bf2f(unsigned short u) {
  union { unsigned int i; float f; } v; v.i = ((unsigned int)u) << 16; return v.f;
}
__device__ __forceinline__ unsigned short f2bf(float f) {
  union { float f; unsigned int i; } v; v.f = f;
  unsigned int r = v.i + 0x7fffu + ((v.i >> 16) & 1u);
  return (unsigned short)(r >> 16);
}
__device__ __forceinline__ unsigned char f2fp8(float f) {
  return (unsigned char)(__builtin_amdgcn_cvt_pk_fp8_f32(f, f, 0, false) & 0xff);
}

// k-permutation within each 128-wide K window: dot(wq,wk) invariant when the
// SAME permutation is applied to both operands; makes each lane's fp8 MFMA
// fragments for ks=2j,2j+1 16B-contiguous -> conflict-free ds_read_b128.
__device__ __forceinline__ int kperm(int k) {
  int ks = k >> 5, quad = (k >> 3) & 3, b = k & 7;
  return ((ks >> 1) << 6) + (quad << 4) + ((ks & 1) << 3) + b;
}

__device__ __forceinline__ void gld_lds16(const void* g, void* l) {
  __builtin_amdgcn_global_load_lds(
      (__attribute__((address_space(1))) void*)(uintptr_t)g,
      (__attribute__((address_space(3))) void*)(uintptr_t)l, 16, 0, 0);
}

// ---------------- 128x128 bf16 GEMM-BT K-loop (m97 pattern) ----------------
__device__ __forceinline__ void gemm_kloop(
    const unsigned short* __restrict__ Ag, const unsigned short* __restrict__ Bg,
    int lda, int ldb, int kdim,
    unsigned short* __restrict__ smA, unsigned short* __restrict__ smB,
    f32x4 acc[4][4])
{
  const int t    = threadIdx.x;
  const int wave = t >> 6;
  const int lane = t & 63;
  const int wm   = (wave >> 1) << 6;
  const int wn   = (wave & 1) << 6;
  const int c16  = lane & 15;
  const int quad = lane >> 4;

  for (int kc = 0; kc < kdim; kc += 64) {
    __syncthreads();
#pragma unroll
    for (int it = 0; it < 4; ++it) {
      int c   = it*256 + t;
      int row = c >> 3;
      int g   = (c & 7) ^ (row & 7);
      const unsigned short* ga = Ag + (size_t)row*lda + kc + g*8;
      const unsigned short* gb = Bg + (size_t)row*ldb + kc + g*8;
      unsigned short* la = smA + (size_t)(it*256 + wave*64)*8;
      unsigned short* lb = smB + (size_t)(it*256 + wave*64)*8;
      gld_lds16(ga, la);
      gld_lds16(gb, lb);
    }
    asm volatile("s_waitcnt vmcnt(0)" ::: "memory");
    __syncthreads();
#pragma unroll
    for (int ks = 0; ks < 2; ++ks) {
      bf16x8 av[4], bv[4];
#pragma unroll
      for (int i = 0; i < 4; ++i) {
        int ra = wm + i*16 + c16;
        av[i] = *(const bf16x8*)(smA + ra*64 + (((ks*4 + quad) ^ (ra & 7)))*8);
        int rb = wn + i*16 + c16;
        bv[i] = *(const bf16x8*)(smB + rb*64 + (((ks*4 + quad) ^ (rb & 7)))*8);
      }
#pragma unroll
      for (int i = 0; i < 4; ++i)
#pragma unroll
        for (int j = 0; j < 4; ++j)
          acc[i][j] = __builtin_amdgcn_mfma_f32_16x16x32_bf16(av[i], bv[j], acc[i][j], 0, 0, 0);
    }
  }
}

__device__ __forceinline__ float blk_sum256(float v, float* red) {
#pragma unroll
  for (int o = 32; o; o >>= 1) v += __shfl_xor(v, o, 64);
  __syncthreads();
  if ((threadIdx.x & 63) == 0) red[threadIdx.x >> 6] = v;
  __syncthreads();
  return red[0] + red[1] + red[2] + red[3];
}

__device__ __forceinline__ float wave_red(float a) {
#pragma unroll
  for (int o = 1; o < 64; o <<= 1) a += __shfl_xor(a, o, 64);
  return a;
}

// -------- fused fp32 -> bf16 bulk convert (6 regions) + zero-fill tail ------
__global__ void __launch_bounds__(256) k_cvt6z(
    const float* __restrict__ s0, unsigned short* __restrict__ d0,
    const float* __restrict__ s1, unsigned short* __restrict__ d1,
    const float* __restrict__ s2, unsigned short* __restrict__ d2,
    const float* __restrict__ s3, unsigned short* __restrict__ d3,
    const float* __restrict__ s4, unsigned short* __restrict__ d4,
    const float* __restrict__ s5, unsigned short* __restrict__ d5,
    float* __restrict__ zbase, int zfloats) {
  int b = blockIdx.x;
  if (b >= 6656) {                       // zero-fill tail blocks
    int i = ((b - 6656)*256 + threadIdx.x)*4;
    if (i + 3 < zfloats) *(float4*)(zbase + i) = float4{0.f,0.f,0.f,0.f};
    return;
  }
  const float* src; unsigned short* dst; int base;
  if      (b < 2048) { src = s0; dst = d0; base = b; }
  else if (b < 4096) { src = s1; dst = d1; base = b - 2048; }
  else if (b < 5120) { src = s2; dst = d2; base = b - 4096; }
  else if (b < 6144) { src = s3; dst = d3; base = b - 5120; }
  else if (b < 6400) { src = s4; dst = d4; base = b - 6144; }
  else               { src = s5; dst = d5; base = b - 6400; }
  int i = (base*256 + threadIdx.x)*4;
  float4 v = *(const float4*)(src + i);
  ushort4 o;
  o.x = f2bf(v.x); o.y = f2bf(v.y); o.z = f2bf(v.z); o.w = f2bf(v.w);
  *(ushort4*)(dst + i) = o;
}

// ---------------- projections (both in one launch): C = X * W^T -------------
// out: fp8 e4m3 (unnormalized), layout [h][b][s][kperm(k)]; nsq += sum C^2.
// LDS exactly 32 KB -> 5 blocks/CU (VGPR 96 allows 20 waves/CU).
__global__ void __launch_bounds__(256) k_proj2(
    const unsigned short* __restrict__ X0, const unsigned short* __restrict__ W0,
    float* __restrict__ n0p, unsigned char* __restrict__ o0p,
    const unsigned short* __restrict__ X1, const unsigned short* __restrict__ W1,
    float* __restrict__ n1p, unsigned char* __restrict__ o1p) {
  __shared__ __align__(16) unsigned char smbuf[32768];
  unsigned short* sm = (unsigned short*)smbuf;
  int which = blockIdx.x >> 11;
  const unsigned short* X = which ? X1 : X0;
  const unsigned short* W = which ? W1 : W0;
  float* nsq = which ? n1p : n0p;
  unsigned char* outp = which ? o1p : o0p;
  int l = blockIdx.x & 2047, x = l & 7, rblk = l >> 3;
  int m0 = (rblk >> 2)*128;
  int n0 = (x*4 + (rblk & 3))*128;
  f32x4 acc[4][4];
#pragma unroll
  for (int i = 0; i < 4; ++i)
#pragma unroll
    for (int j = 0; j < 4; ++j) acc[i][j] = f32x4{0.f,0.f,0.f,0.f};
  gemm_kloop(X + (size_t)m0*D_, W + (size_t)n0*D_, D_, D_, D_, sm, sm + 128*64, acc);
  const int t = threadIdx.x, wave = t>>6, lane = t&63;
  const int wm = (wave>>1)*64, wn = (wave&1)*64, quad = lane>>4, c16 = lane&15;
  const int h = n0 >> 10;
  unsigned char* sm8 = smbuf;
  __syncthreads();          // staging done; reuse sm as fp8 output tile (18 KB)
#pragma unroll
  for (int i = 0; i < 4; ++i)
#pragma unroll
    for (int r = 0; r < 4; ++r) {
      int mloc = wm + i*16 + quad*4 + r;
      float sq = 0.f;
#pragma unroll
      for (int j = 0; j < 4; ++j) {
        float v = acc[i][j][r];
        sm8[mloc*PROW + kperm(wn + j*16 + c16)] = f2fp8(v);
        sq += v*v;
      }
      sq += __shfl_xor(sq, 1, 64); sq += __shfl_xor(sq, 2, 64);
      sq += __shfl_xor(sq, 4, 64); sq += __shfl_xor(sq, 8, 64);
      if (c16 == 0) {
        int m = m0 + mloc;
        atomicAdd(&nsq[(size_t)(h*B_ + (m & 3))*S_ + (m >> 2)], sq);
      }
    }
  __syncthreads();
  // coalesced fp8 stores: 4 passes x (32 rows x 8 col-granules)
  const int cg = t & 7, rsub = t >> 3;
#pragma unroll
  for (int c = 0; c < 4; ++c) {
    int mloc = c*32 + rsub;
    int m = m0 + mloc, s = m >> 2, b = m & 3;
    uint4 val = *(const uint4*)(sm8 + mloc*PROW + cg*16);
    *(uint4*)(outp + ((size_t)(h*B_ + b)*S_ + s)*K_ + (n0 & (K_-1)) + cg*16) = val;
  }
}

// ---------------- QK^T (fp8, k-permuted): row sums l[q] + E=exp(dot) fp8 ----
// hb-per-XCD swizzle (XCD x owns hb {2x,2x+1}); s outer / q inner for L2
// residency. LDS exactly 32 KB -> 5 blocks/CU (20 waves = VGPR limit).
__global__ void __launch_bounds__(256) k_qkA(const unsigned char* __restrict__ wqa,
    const unsigned char* __restrict__ wka, const float* __restrict__ nq,
    const float* __restrict__ nk, float* __restrict__ lrow,
    unsigned char* __restrict__ E) {
  __shared__ __align__(16) unsigned char smbuf[32768];
  unsigned char* smA = smbuf;                     // 16 KB
  unsigned char* smB = smA + 128*128;             // 16 KB
  int l = blockIdx.x, x = l & 7, rblk = l >> 3;   // rblk 0..511
  int hb = x*2 + (rblk >> 8);                     // 2 hb per XCD
  int r2 = rblk & 255;
  int s0 = (r2 >> 4)*128;                         // s outer
  int q0 = (r2 & 15)*128;                         // q inner (reuses wka tile)
  const unsigned char* A  = wqa + (size_t)hb*S_*K_ + (size_t)q0*K_;
  const unsigned char* Bm = wka + (size_t)hb*S_*K_ + (size_t)s0*K_;
  const int t = threadIdx.x, wave = t>>6, lane = t&63;
  const int wm = (wave>>1)*64, wn = (wave&1)*64, quad = lane>>4, c16 = lane&15;
  f32x4 acc[4][4];
#pragma unroll
  for (int i = 0; i < 4; ++i)
#pragma unroll
    for (int j = 0; j < 4; ++j) acc[i][j] = f32x4{0.f,0.f,0.f,0.f};

  for (int kc = 0; kc < K_; kc += 128) {
    __syncthreads();
#pragma unroll
    for (int it = 0; it < 4; ++it) {
      int c   = it*256 + t;
      int row = c >> 3;
      int g   = (c & 7) ^ (row & 7);
      gld_lds16(A  + (size_t)row*K_ + kc + g*16, smA + (size_t)(it*256 + wave*64)*16);
      gld_lds16(Bm + (size_t)row*K_ + kc + g*16, smB + (size_t)(it*256 + wave*64)*16);
    }
    asm volatile("s_waitcnt vmcnt(0)" ::: "memory");
    __syncthreads();
#pragma unroll
    for (int j2 = 0; j2 < 2; ++j2) {
      uint4 a4[4], b4[4];
#pragma unroll
      for (int i = 0; i < 4; ++i) {
        int ra = wm + i*16 + c16;
        a4[i] = *(const uint4*)(smA + ra*128 + (((j2*4 + quad) ^ (ra & 7)))*16);
        int rb = wn + i*16 + c16;
        b4[i] = *(const uint4*)(smB + rb*128 + (((j2*4 + quad) ^ (rb & 7)))*16);
      }
#pragma unroll
      for (int hh = 0; hh < 2; ++hh)
#pragma unroll
        for (int i = 0; i < 4; ++i)
#pragma unroll
          for (int j = 0; j < 4; ++j)
            acc[i][j] = __builtin_amdgcn_mfma_f32_16x16x32_fp8_fp8(
                ((const long*)&a4[i])[hh], ((const long*)&b4[j])[hh],
                acc[i][j], 0, 0, 0);
    }
  }

  float rk4[4];
#pragma unroll
  for (int j = 0; j < 4; ++j)
    rk4[j] = rsqrtf(nk[(size_t)hb*S_ + s0 + wn + j*16 + c16]);
  unsigned char* sm8 = smbuf;
  __syncthreads();          // staging done; reuse sm as fp8 E tile (18 KB)
#pragma unroll
  for (int i = 0; i < 4; ++i)
#pragma unroll
    for (int r = 0; r < 4; ++r) {
      int qloc = wm + i*16 + quad*4 + r;
      float rq = rsqrtf(nq[(size_t)hb*S_ + q0 + qloc]);
      float rs = 0.f;
#pragma unroll
      for (int j = 0; j < 4; ++j) {
        float e = __expf(acc[i][j][r] * rq * rk4[j]);
        rs += e;
        sm8[qloc*PROW + wn + j*16 + c16] = f2fp8(e);
      }
      rs += __shfl_xor(rs, 1, 64); rs += __shfl_xor(rs, 2, 64);
      rs += __shfl_xor(rs, 4, 64); rs += __shfl_xor(rs, 8, 64);
      if (c16 == 0) atomicAdd(&lrow[(size_t)hb*S_ + q0 + qloc], rs);
    }
  __syncthreads();
  const int cg = t & 7, rsub = t >> 3;
#pragma unroll
  for (int c = 0; c < 4; ++c) {
    int qloc = c*32 + rsub;
    uint4 val = *(const uint4*)(sm8 + qloc*PROW + cg*16);
    *(uint4*)(E + ((size_t)hb*S_ + qloc + q0)*S_ + s0 + cg*16) = val;
  }
}

// ---------------- colsum from materialized fp8 E (vectorized) ---------------
__global__ void __launch_bounds__(256) k_colsumE(const unsigned char* __restrict__ E,
    const float* __restrict__ lrow, float* __restrict__ colsum,
    float* __restrict__ p0) {
  __shared__ float il[128];
  int hb = blockIdx.x, qc = blockIdx.y;   // grid (HB_, 16): 128 q rows/blk
  int t  = threadIdx.x;
  if (t < 128) il[t] = 1.f / lrow[(size_t)hb*S_ + qc*128 + t];
  __syncthreads();
  const unsigned char* Eb = E + (size_t)hb*S_*S_ + (size_t)(qc*128)*S_ + t*8;
  float acc8[8] = {0,0,0,0,0,0,0,0};
  for (int qi = 0; qi < 128; ++qi) {
    uint2 u = *(const uint2*)(Eb + (size_t)qi*S_);
    float w = il[qi];
    f32x2 v01 = __builtin_amdgcn_cvt_pk_f32_fp8(u.x, false);
    f32x2 v23 = __builtin_amdgcn_cvt_pk_f32_fp8(u.x, true);
    f32x2 v45 = __builtin_amdgcn_cvt_pk_f32_fp8(u.y, false);
    f32x2 v67 = __builtin_amdgcn_cvt_pk_f32_fp8(u.y, true);
    float v8[8] = {v01.x, v01.y, v23.x, v23.y, v45.x, v45.y, v67.x, v67.y};
#pragma unroll
    for (int k = 0; k < 8; ++k) acc8[k] += v8[k] * w;
    if (qc == 0 && qi == 0) {
#pragma unroll
      for (int k = 0; k < 8; ++k) p0[(size_t)hb*S_ + t*8 + k] = v8[k] * w;
    }
  }
#pragma unroll
  for (int k = 0; k < 8; ++k)
    atomicAdd(&colsum[(size_t)hb*S_ + t*8 + k], acc8[k]);
}

// ---------------- mid0: c[hb][d] = sum_s aff0[s]*kv[s,b,d]  (partial, atomic)
__global__ void __launch_bounds__(256) k_mid0(const float* __restrict__ p0,
    const float* __restrict__ colsum, const float* __restrict__ kv,
    float* __restrict__ cbuf) {
  __shared__ float aff[128];
  int hb = blockIdx.x, sc = blockIdx.y;
  int b = hb & 3;
  int t = threadIdx.x;
  if (t < 128) {
    int s = sc*128 + t;
    aff[t] = p0[(size_t)hb*S_ + s] / (1e-9f + colsum[(size_t)hb*S_ + s]);
  }
  __syncthreads();
  float acc = 0.f;
#pragma unroll 4
  for (int i = 0; i < 128; ++i) {
    int s = sc*128 + i;
    acc += aff[i] * kv[((size_t)s*B_ + b)*D_ + t];
  }
  atomicAdd(&cbuf[hb*D_ + t], acc);
}

// ---------------- mid1a: o0 -> qmo -> ru  (grid HB_, wave-per-row) ----------
__global__ void __launch_bounds__(256) k_mid1a(const float* __restrict__ cbuf,
    const float* __restrict__ mem, const float* __restrict__ WV,
    const float* __restrict__ Wt, float* __restrict__ ruW) {
  __shared__ float cS[D_], qmo[D_];
  int hb = blockIdx.x, h = hb >> 2, b = hb & 3;
  int t = threadIdx.x, wave = t >> 6, lane = t & 63;
  cS[t] = cbuf[hb*D_ + t];
  __syncthreads();
  float4 cv = *(const float4*)(cS + lane*4);
  for (int rr = 0; rr < 64; ++rr) {
    int e = wave*64 + rr;
    float4 w = *(const float4*)(WV + ((size_t)h*D_ + e)*D_ + lane*4);
    float a = wave_red(cv.x*w.x + cv.y*w.y + cv.z*w.z + cv.w*w.w);
    if (lane == 0) qmo[e] = mem[(size_t)b*D_ + e] - a;
  }
  __syncthreads();
  float4 qv = *(const float4*)(qmo + lane*4);
  for (int rr = 0; rr < 64; ++rr) {
    int e = wave*64 + rr;
    float4 w = *(const float4*)(Wt + ((size_t)h*D_ + e)*D_ + lane*4);
    float a = wave_red(qv.x*w.x + qv.y*w.y + qv.z*w.z + qv.w*w.w);
    if (lane == 0) ruW[hb*D_ + e] = fmaxf(a, 0.f);
  }
}

// ---------------- mid1b: hmid (grid HB_ x 8, wave-per-row) ------------------
__global__ void __launch_bounds__(256) k_mid1b(const float* __restrict__ ruW,
    const float* __restrict__ e1w, const float* __restrict__ e1b,
    float* __restrict__ hmW) {
  __shared__ float ru[D_];
  int hb = blockIdx.x, kc = blockIdx.y, h = hb >> 2;
  int t = threadIdx.x, wave = t >> 6, lane = t & 63;
  ru[t] = ruW[hb*D_ + t];
  __syncthreads();
  float4 rv = *(const float4*)(ru + lane*4);
  for (int rr = 0; rr < 32; ++rr) {
    int k = kc*128 + wave*32 + rr;
    float4 w = *(const float4*)(e1w + ((size_t)h*K_ + k)*D_ + lane*4);
    float a = wave_red(rv.x*w.x + rv.y*w.y + rv.z*w.z + rv.w*w.w);
    if (lane == 0) hmW[hb*K_ + k] = fmaxf(a + e1b[(size_t)h*K_ + k], 0.f);
  }
}

// ---------------- mid1c: s2 (grid HB_ x 8, wave-per-row) --------------------
__global__ void __launch_bounds__(256) k_mid1c(const float* __restrict__ hmW,
    const float* __restrict__ e2w, const float* __restrict__ e2b,
    float* __restrict__ s2W) {
  __shared__ float hm[K_];
  int hb = blockIdx.x, dc = blockIdx.y, h = hb >> 2;
  int t = threadIdx.x, wave = t >> 6, lane = t & 63;
  for (int k = t; k < K_; k += 256) hm[k] = hmW[hb*K_ + k];
  __syncthreads();
  for (int rr = 0; rr < 8; ++rr) {
    int d = dc*32 + wave*8 + rr;
    const float* row = e2w + ((size_t)h*D_ + d)*K_;
    float a = 0.f;
#pragma unroll
    for (int p = 0; p < 4; ++p) {
      float4 w = *(const float4*)(row + (p*64 + lane)*4);
      float4 hv = *(const float4*)(hm + (p*64 + lane)*4);
      a += w.x*hv.x + w.y*hv.y + w.z*hv.z + w.w*hv.w;
    }
    a = wave_red(a);
    if (lane == 0) s2W[hb*D_ + d] = a + e2b[(size_t)h*D_ + d];
  }
}

// ---------------- mid1d: LN(ru + s2) -> xh0 (grid HB_) ----------------------
__global__ void __launch_bounds__(256) k_mid1d(const float* __restrict__ ruW,
    const float* __restrict__ s2W, const float* __restrict__ eg,
    const float* __restrict__ ebias, float* __restrict__ xh0) {
  __shared__ float red[4];
  int hb = blockIdx.x, h = hb >> 2;
  int t = threadIdx.x;
  float tv = ruW[hb*D_ + t] + s2W[hb*D_ + t];
  float mean = blk_sum256(tv, red) * (1.f/D_);
  float dv = tv - mean;
  float var = blk_sum256(dv*dv, red) * (1.f/D_);
  xh0[hb*D_ + t] = dv * rsqrtf(var + 1e-5f) * eg[(size_t)h*D_ + t] + ebias[(size_t)h*D_ + t];
}

// ---------------- mid2: srcc2 (grid B_ x 8, wave-per-row) -------------------
__global__ void __launch_bounds__(256) k_mid2(const float* __restrict__ xh0,
    const float* __restrict__ Wout, float* __restrict__ srcc2) {
  __shared__ float cat[NH_*D_];
  int b = blockIdx.x, dc = blockIdx.y;
  int t = threadIdx.x, wave = t >> 6, lane = t & 63;
  for (int n = t; n < NH_*D_; n += 256)
    cat[n] = xh0[((size_t)(n >> 8)*B_ + b)*D_ + (n & 255)];
  __syncthreads();
  for (int rr = 0; rr < 8; ++rr) {
    int d = dc*32 + wave*8 + rr;
    const float* row = Wout + (size_t)d*(NH_*D_);
    float a = 0.f;
#pragma unroll
    for (int p = 0; p < 4; ++p) {
      float4 w = *(const float4*)(row + (p*64 + lane)*4);
      float4 cv = *(const float4*)(cat + (p*64 + lane)*4);
      a += w.x*cv.x + w.y*cv.y + w.z*cv.z + w.w*cv.w;
    }
    a = wave_red(a);
    if (lane == 0) srcc2[b*D_ + d] = a;
  }
}

// ---------------- F1: x = LN(memory + srcc2) -> fp32 + bf16 -----------------
__global__ void __launch_bounds__(256) k_f1(const float* __restrict__ mem,
    const float* __restrict__ srcc2, const float* __restrict__ g,
    const float* __restrict__ bb, float* __restrict__ xf,
    unsigned short* __restrict__ xb) {
  __shared__ float red[4];
  int m = blockIdx.x, t = threadIdx.x;
  float v = mem[(size_t)m*D_ + t] + srcc2[(m & 3)*D_ + t];
  float mean = blk_sum256(v, red) * (1.f/D_);
  float d = v - mean;
  float var = blk_sum256(d*d, red) * (1.f/D_);
  float y = d * rsqrtf(var + 1e-5f) * g[t] + bb[t];
  xf[(size_t)m*D_ + t] = y;
  xb[(size_t)m*D_ + t] = f2bf(y);
}

// ---------------- F2: h1 = relu(x @ l1w^T + l1b)  bf16 (XCD-swizzled) -------
__global__ void __launch_bounds__(256) k_f2(const unsigned short* __restrict__ xb,
    const unsigned short* __restrict__ l1wb, const float* __restrict__ l1b,
    unsigned short* __restrict__ h1) {
  __shared__ __align__(16) unsigned short sm[128*LDSROW];
  int l = blockIdx.x;
  int n0 = (l & 7)*128, m0 = (l >> 3)*128;
  f32x4 acc[4][4];
#pragma unroll
  for (int i = 0; i < 4; ++i)
#pragma unroll
    for (int j = 0; j < 4; ++j) acc[i][j] = f32x4{0.f,0.f,0.f,0.f};
  gemm_kloop(xb + (size_t)m0*D_, l1wb + (size_t)n0*D_, D_, D_, D_, sm, sm + 128*64, acc);
  const int t = threadIdx.x, wave = t>>6, lane = t&63;
  const int wm = (wave>>1)*64, wn = (wave&1)*64, quad = lane>>4, c16 = lane&15;
  __syncthreads();
#pragma unroll
  for (int i = 0; i < 4; ++i)
#pragma unroll
    for (int r = 0; r < 4; ++r) {
      int mloc = wm + i*16 + quad*4 + r;
#pragma unroll
      for (int j = 0; j < 4; ++j) {
        int n = n0 + wn + j*16 + c16;
        sm[mloc*LDSROW + wn + j*16 + c16] = f2bf(fmaxf(acc[i][j][r] + l1b[n], 0.f));
      }
    }
  __syncthreads();
  const int col8 = (t & 15)*8, rsub = t >> 4;
#pragma unroll
  for (int c = 0; c < 8; ++c) {
    int mloc = c*16 + rsub;
    uint4 val = *(const uint4*)(sm + mloc*LDSROW + col8);
    *(uint4*)(h1 + (size_t)(m0 + mloc)*FF_ + n0 + col8) = val;
  }
}

// ---------------- F3: split-K 4x into four buffers (no atomics) -------------
__global__ void __launch_bounds__(256) k_f3(const unsigned short* __restrict__ h1,
    const unsigned short* __restrict__ l2wb, float* __restrict__ y0,
    float* __restrict__ y1, float* __restrict__ y2, float* __restrict__ y3) {
  __shared__ __align__(16) unsigned short smA[128*64], smB[128*64];
  int l = blockIdx.x;                 // 512 blocks: z = K-quarter, n (2), m (64)
  int z = l & 3, n0 = ((l >> 2) & 1)*128, m0 = (l >> 3)*128;
  float* dst = (z == 0) ? y0 : (z == 1) ? y1 : (z == 2) ? y2 : y3;
  f32x4 acc[4][4];
#pragma unroll
  for (int i = 0; i < 4; ++i)
#pragma unroll
    for (int j = 0; j < 4; ++j) acc[i][j] = f32x4{0.f,0.f,0.f,0.f};
  gemm_kloop(h1 + (size_t)m0*FF_ + z*256, l2wb + (size_t)n0*FF_ + z*256,
             FF_, FF_, 256, smA, smB, acc);
  const int t = threadIdx.x, wave = t>>6, lane = t&63;
  const int wm = (wave>>1)*64, wn = (wave&1)*64, quad = lane>>4, c16 = lane&15;
#pragma unroll
  for (int i = 0; i < 4; ++i)
#pragma unroll
    for (int r = 0; r < 4; ++r) {
      int m = m0 + wm + i*16 + quad*4 + r;
#pragma unroll
      for (int j = 0; j < 4; ++j) {
        int n = n0 + wn + j*16 + c16;
        dst[(size_t)m*D_ + n] = acc[i][j][r];
      }
    }
}

// ---------------- F4: out = LN(y0+y1+y2+y3 + l2b + x) -----------------------
__global__ void __launch_bounds__(256) k_f4(const float* __restrict__ y0,
    const float* __restrict__ y1, const float* __restrict__ y2,
    const float* __restrict__ y3, const float* __restrict__ l2b,
    const float* __restrict__ xf, const float* __restrict__ g,
    const float* __restrict__ bb, float* __restrict__ out) {
  __shared__ float red[4];
  int m = blockIdx.x, t = threadIdx.x;
  size_t idx = (size_t)m*D_ + t;
  float v = y0[idx] + y1[idx] + y2[idx] + y3[idx] + l2b[t] + xf[idx];
  float mean = blk_sum256(v, red) * (1.f/D_);
  float d = v - mean;
  float var = blk_sum256(d*d, red) * (1.f/D_);
  out[idx] = d * rsqrtf(var + 1e-5f) * g[t] + bb[t];
}

// ---------------- workspace layout (bytes) ----------------------------------
constexpr size_t SZ_ACT  = (size_t)HB_*S_*K_;                   // 32 MiB (fp8)
constexpr size_t OFF_WQA = 0;
constexpr size_t OFF_WKA = OFF_WQA + SZ_ACT;
constexpr size_t OFF_KVB = OFF_WKA + SZ_ACT;
constexpr size_t OFF_QB  = OFF_KVB + (size_t)M_*D_*2;
constexpr size_t OFF_WKW = OFF_QB  + (size_t)M_*D_*2;
constexpr size_t OFF_WQW = OFF_WKW + (size_t)NH_*K_*D_*2;
constexpr size_t OFF_L1W = OFF_WQW + (size_t)NH_*K_*D_*2;
constexpr size_t OFF_L2W = OFF_L1W + (size_t)FF_*D_*2;
constexpr size_t OFF_XB  = OFF_L2W + (size_t)D_*FF_*2;
constexpr size_t OFF_H1  = OFF_XB  + (size_t)M_*D_*2;
constexpr size_t OFF_XF  = OFF_H1  + (size_t)M_*FF_*2;
constexpr size_t OFF_YF0 = OFF_XF  + (size_t)M_*D_*4;
constexpr size_t OFF_YF1 = OFF_YF0 + (size_t)M_*D_*4;
constexpr size_t OFF_YF2 = OFF_YF1 + (size_t)M_*D_*4;
constexpr size_t OFF_YF3 = OFF_YF2 + (size_t)M_*D_*4;
constexpr size_t OFF_NQ  = OFF_YF3 + (size_t)M_*D_*4;           // zero region
constexpr size_t OFF_NK  = OFF_NQ + (size_t)HB_*S_*4;
constexpr size_t OFF_L   = OFF_NK + (size_t)HB_*S_*4;
constexpr size_t OFF_CS  = OFF_L  + (size_t)HB_*S_*4;
constexpr size_t OFF_CB  = OFF_CS + (size_t)HB_*S_*4;
constexpr size_t ZERO_BYTES = (size_t)HB_*S_*4*4 + (size_t)HB_*D_*4;
constexpr size_t OFF_P0  = OFF_CB + (size_t)HB_*D_*4;
constexpr size_t OFF_XH0 = OFF_P0 + (size_t)HB_*S_*4;
constexpr size_t OFF_SC2 = OFF_XH0 + (size_t)HB_*D_*4;
constexpr size_t OFF_RU  = OFF_SC2 + (size_t)B_*D_*4;
constexpr size_t OFF_HM  = OFF_RU  + (size_t)HB_*D_*4;
constexpr size_t OFF_S2  = OFF_HM  + (size_t)HB_*K_*4;
constexpr size_t OFF_E   = OFF_S2  + (size_t)HB_*D_*4;
constexpr size_t SZ_E    = (size_t)HB_*S_*S_;                   // 64 MiB (fp8)
constexpr size_t NEED_ALL = OFF_E + SZ_E;                       // ~202 MiB

extern "C" void kernel_launch(void* const* d_in, const int* in_sizes, int n_in,
                              void* d_out, int out_size, void* d_ws, size_t ws_size,
                              hipStream_t stream) {
  (void)in_sizes; (void)out_size;
  if (n_in < 21) return;
  const float* srcc = (const float*)d_in[0];
  const float* mem  = (const float*)d_in[1];
  const float* WK   = (const float*)d_in[2];
  const float* WQ   = (const float*)d_in[3];
  const float* WV   = (const float*)d_in[4];
  const float* Wt   = (const float*)d_in[5];
  const float* e1w  = (const float*)d_in[6];
  const float* e1b  = (const float*)d_in[7];
  const float* e2w  = (const float*)d_in[8];
  const float* e2b  = (const float*)d_in[9];
  const float* eg   = (const float*)d_in[10];
  const float* eb   = (const float*)d_in[11];
  const float* Wout = (const float*)d_in[12];
  const float* l1w  = (const float*)d_in[13];
  const float* l1b  = (const float*)d_in[14];
  const float* l2w  = (const float*)d_in[15];
  const float* l2b  = (const float*)d_in[16];
  const float* n1g  = (const float*)d_in[17];
  const float* n1b  = (const float*)d_in[18];
  const float* n3g  = (const float*)d_in[19];
  const float* n3b  = (const float*)d_in[20];

  char* ws = (char*)d_ws;
  if (ws_size < NEED_ALL) {
    fprintf(stderr, "kernel_launch: ws_size=%zu < required %zu bytes — aborting\n",
            ws_size, NEED_ALL);
    return;
  }

  unsigned char*  wqa  = (unsigned char*)(ws + OFF_WQA);
  unsigned char*  wka  = (unsigned char*)(ws + OFF_WKA);
  unsigned short* kvb  = (unsigned short*)(ws + OFF_KVB);
  unsigned short* qb   = (unsigned short*)(ws + OFF_QB);
  unsigned short* wkw  = (unsigned short*)(ws + OFF_WKW);
  unsigned short* wqw  = (unsigned short*)(ws + OFF_WQW);
  unsigned short* l1wb = (unsigned short*)(ws + OFF_L1W);
  unsigned short* l2wb = (unsigned short*)(ws + OFF_L2W);
  unsigned short* xb   = (unsigned short*)(ws + OFF_XB);
  unsigned short* h1   = (unsigned short*)(ws + OFF_H1);
  float* xf    = (float*)(ws + OFF_XF);
  float* yf0   = (float*)(ws + OFF_YF0);
  float* yf1   = (float*)(ws + OFF_YF1);
  float* yf2   = (float*)(ws + OFF_YF2);
  float* yf3   = (float*)(ws + OFF_YF3);
  float* nq    = (float*)(ws + OFF_NQ);
  float* nk    = (float*)(ws + OFF_NK);
  float* lrow  = (float*)(ws + OFF_L);
  float* cs    = (float*)(ws + OFF_CS);
  float* cbuf  = (float*)(ws + OFF_CB);
  float* p0    = (float*)(ws + OFF_P0);
  float* xh0   = (float*)(ws + OFF_XH0);
  float* sc2   = (float*)(ws + OFF_SC2);
  float* ruW   = (float*)(ws + OFF_RU);
  float* hmW   = (float*)(ws + OFF_HM);
  float* s2W   = (float*)(ws + OFF_S2);
  unsigned char* E = (unsigned char*)(ws + OFF_E);

  // fp32 -> bf16 conversions + zero-fill of atomic buffers, one launch
  int zfloats = (int)(ZERO_BYTES/4);
  int zblocks = (zfloats + 1023)/1024;
  k_cvt6z<<<6656 + zblocks, 256, 0, stream>>>(srcc, kvb, mem, qb, WK, wkw,
                                              WQ, wqw, l1w, l1wb, l2w, l2wb,
                                              nq, zfloats);

  // both projections (bf16 GEMM -> fp8 out, k-permuted) + row norm^2
  k_proj2<<<4096, 256, 0, stream>>>(kvb, wkw, nk, wka, qb, wqw, nq, wqa);

  // QK^T fp8 (single pass, fp8 E, hb-per-XCD locality) + weighted colsum
  k_qkA<<<4096, 256, 0, stream>>>(wqa, wka, nq, nk, lrow, E);
  k_colsumE<<<dim3(HB_, 16), 256, 0, stream>>>(E, lrow, cs, p0);

  // q=0 tail of the RMA block
  k_mid0<<<dim3(HB_, S_/128), 256, 0, stream>>>(p0, cs, srcc, cbuf);
  k_mid1a<<<HB_, 256, 0, stream>>>(cbuf, mem, WV, Wt, ruW);
  k_mid1b<<<dim3(HB_, 8), 256, 0, stream>>>(ruW, e1w, e1b, hmW);
  k_mid1c<<<dim3(HB_, 8), 256, 0, stream>>>(hmW, e2w, e2b, s2W);
  k_mid1d<<<HB_, 256, 0, stream>>>(ruW, s2W, eg, eb, xh0);
  k_mid2<<<dim3(B_, 8), 256, 0, stream>>>(xh0, Wout, sc2);

  // decoder FFN
  k_f1<<<M_, 256, 0, stream>>>(mem, sc2, n1g, n1b, xf, xb);
  k_f2<<<512, 256, 0, stream>>>(xb, l1wb, l1b, h1);
  k_f3<<<512, 256, 0, stream>>>(h1, l2wb, yf0, yf1, yf2, yf3);
  k_f4<<<M_, 256, 0, stream>>>(yf0, yf1, yf2, yf3, l2b, xf, n3g, n3b,
                               (float*)d_out);
}

// Round 10
// 587.324 us; speedup vs baseline: 1.0299x; 1.0299x over previous
//
#include <hip/hip_runtime.h>
#include <stdint.h>
#include <stdio.h>

#define S_  2048
#define B_  4
#define D_  256
#define NH_ 4
#define K_  1024
#define FF_ 1024
#define M_  (S_*B_)      // 8192 rows (s,b)
#define HB_ (NH_*B_)     // 16 (h,b) pairs

// bf16 LDS tile row stride (shorts): 128 data + 8 pad (272 B rows).
#define LDSROW 136
// fp8 LDS tile row stride (bytes): 128 data + 16 pad, 16B-aligned.
#define PROW 144
// fp8 E-tile row stride for the 128x64 qkA tile (64 data + 16 pad).
#define EROW 80

typedef float  f32x4  __attribute__((ext_vector_type(4)));
typedef float  f32x2  __attribute__((ext_vector_type(2)));
typedef __bf16 bf16x8 __attribute__((ext_vector_type(8)));

__device__ __forceinline__ float bf2f(unsigned short u) {
  union { unsigned int i; float f; } v; v.i = ((unsigned int)u) << 16; return v.f;
}
__device__ __forceinline__ unsigned short f2bf(float f) {
  union { float f; unsigned int i; } v; v.f = f;
  unsigned int r = v.i + 0x7fffu + ((v.i >> 16) & 1u);
  return (unsigned short)(r >> 16);
}
__device__ __forceinline__ unsigned char f2fp8(float f) {
  return (unsigned char)(__builtin_amdgcn_cvt_pk_fp8_f32(f, f, 0, false) & 0xff);
}

// k-permutation within each 128-wide K window: dot(wq,wk) invariant when the
// SAME permutation is applied to both operands; makes each lane's fp8 MFMA
// fragments for ks=2j,2j+1 16B-contiguous -> conflict-free ds_read_b128.
__device__ __forceinline__ int kperm(int k) {
  int ks = k >> 5, quad = (k >> 3) & 3, b = k & 7;
  return ((ks >> 1) << 6) + (quad << 4) + ((ks & 1) << 3) + b;
}

__device__ __forceinline__ void gld_lds16(const void* g, void* l) {
  __builtin_amdgcn_global_load_lds(
      (__attribute__((address_space(1))) void*)(uintptr_t)g,
      (__attribute__((address_space(3))) void*)(uintptr_t)l, 16, 0, 0);
}

// ---------------- 128x128 bf16 GEMM-BT K-loop (m97 pattern) ----------------
__device__ __forceinline__ void gemm_kloop(
    const unsigned short* __restrict__ Ag, const unsigned short* __restrict__ Bg,
    int lda, int ldb, int kdim,
    unsigned short* __restrict__ smA, unsigned short* __restrict__ smB,
    f32x4 acc[4][4])
{
  const int t    = threadIdx.x;
  const int wave = t >> 6;
  const int lane = t & 63;
  const int wm   = (wave >> 1) << 6;
  const int wn   = (wave & 1) << 6;
  const int c16  = lane & 15;
  const int quad = lane >> 4;

  for (int kc = 0; kc < kdim; kc += 64) {
    __syncthreads();
#pragma unroll
    for (int it = 0; it < 4; ++it) {
      int c   = it*256 + t;
      int row = c >> 3;
      int g   = (c & 7) ^ (row & 7);
      const unsigned short* ga = Ag + (size_t)row*lda + kc + g*8;
      const unsigned short* gb = Bg + (size_t)row*ldb + kc + g*8;
      unsigned short* la = smA + (size_t)(it*256 + wave*64)*8;
      unsigned short* lb = smB + (size_t)(it*256 + wave*64)*8;
      gld_lds16(ga, la);
      gld_lds16(gb, lb);
    }
    asm volatile("s_waitcnt vmcnt(0)" ::: "memory");
    __syncthreads();
#pragma unroll
    for (int ks = 0; ks < 2; ++ks) {
      bf16x8 av[4], bv[4];
#pragma unroll
      for (int i = 0; i < 4; ++i) {
        int ra = wm + i*16 + c16;
        av[i] = *(const bf16x8*)(smA + ra*64 + (((ks*4 + quad) ^ (ra & 7)))*8);
        int rb = wn + i*16 + c16;
        bv[i] = *(const bf16x8*)(smB + rb*64 + (((ks*4 + quad) ^ (rb & 7)))*8);
      }
#pragma unroll
      for (int i = 0; i < 4; ++i)
#pragma unroll
        for (int j = 0; j < 4; ++j)
          acc[i][j] = __builtin_amdgcn_mfma_f32_16x16x32_bf16(av[i], bv[j], acc[i][j], 0, 0, 0);
    }
  }
}

__device__ __forceinline__ float blk_sum256(float v, float* red) {
#pragma unroll
  for (int o = 32; o; o >>= 1) v += __shfl_xor(v, o, 64);
  __syncthreads();
  if ((threadIdx.x & 63) == 0) red[threadIdx.x >> 6] = v;
  __syncthreads();
  return red[0] + red[1] + red[2] + red[3];
}

__device__ __forceinline__ float wave_red(float a) {
#pragma unroll
  for (int o = 1; o < 64; o <<= 1) a += __shfl_xor(a, o, 64);
  return a;
}

// -------- fused fp32 -> bf16 bulk convert (6 regions) + zero-fill tail ------
__global__ void __launch_bounds__(256) k_cvt6z(
    const float* __restrict__ s0, unsigned short* __restrict__ d0,
    const float* __restrict__ s1, unsigned short* __restrict__ d1,
    const float* __restrict__ s2, unsigned short* __restrict__ d2,
    const float* __restrict__ s3, unsigned short* __restrict__ d3,
    const float* __restrict__ s4, unsigned short* __restrict__ d4,
    const float* __restrict__ s5, unsigned short* __restrict__ d5,
    float* __restrict__ zbase, int zfloats) {
  int b = blockIdx.x;
  if (b >= 6656) {                       // zero-fill tail blocks
    int i = ((b - 6656)*256 + threadIdx.x)*4;
    if (i + 3 < zfloats) *(float4*)(zbase + i) = float4{0.f,0.f,0.f,0.f};
    return;
  }
  const float* src; unsigned short* dst; int base;
  if      (b < 2048) { src = s0; dst = d0; base = b; }
  else if (b < 4096) { src = s1; dst = d1; base = b - 2048; }
  else if (b < 5120) { src = s2; dst = d2; base = b - 4096; }
  else if (b < 6144) { src = s3; dst = d3; base = b - 5120; }
  else if (b < 6400) { src = s4; dst = d4; base = b - 6144; }
  else               { src = s5; dst = d5; base = b - 6400; }
  int i = (base*256 + threadIdx.x)*4;
  float4 v = *(const float4*)(src + i);
  ushort4 o;
  o.x = f2bf(v.x); o.y = f2bf(v.y); o.z = f2bf(v.z); o.w = f2bf(v.w);
  *(ushort4*)(dst + i) = o;
}

// ---------------- projections (both in one launch): C = X * W^T -------------
// out: fp8 e4m3 (unnormalized), layout [h][b][s][kperm(k)]; nsq += sum C^2.
__global__ void __launch_bounds__(256) k_proj2(
    const unsigned short* __restrict__ X0, const unsigned short* __restrict__ W0,
    float* __restrict__ n0p, unsigned char* __restrict__ o0p,
    const unsigned short* __restrict__ X1, const unsigned short* __restrict__ W1,
    float* __restrict__ n1p, unsigned char* __restrict__ o1p) {
  __shared__ __align__(16) unsigned char smbuf[32768];
  unsigned short* sm = (unsigned short*)smbuf;
  int which = blockIdx.x >> 11;
  const unsigned short* X = which ? X1 : X0;
  const unsigned short* W = which ? W1 : W0;
  float* nsq = which ? n1p : n0p;
  unsigned char* outp = which ? o1p : o0p;
  int l = blockIdx.x & 2047, x = l & 7, rblk = l >> 3;
  int m0 = (rblk >> 2)*128;
  int n0 = (x*4 + (rblk & 3))*128;
  f32x4 acc[4][4];
#pragma unroll
  for (int i = 0; i < 4; ++i)
#pragma unroll
    for (int j = 0; j < 4; ++j) acc[i][j] = f32x4{0.f,0.f,0.f,0.f};
  gemm_kloop(X + (size_t)m0*D_, W + (size_t)n0*D_, D_, D_, D_, sm, sm + 128*64, acc);
  const int t = threadIdx.x, wave = t>>6, lane = t&63;
  const int wm = (wave>>1)*64, wn = (wave&1)*64, quad = lane>>4, c16 = lane&15;
  const int h = n0 >> 10;
  unsigned char* sm8 = smbuf;
  __syncthreads();          // staging done; reuse sm as fp8 output tile (18 KB)
#pragma unroll
  for (int i = 0; i < 4; ++i)
#pragma unroll
    for (int r = 0; r < 4; ++r) {
      int mloc = wm + i*16 + quad*4 + r;
      float sq = 0.f;
#pragma unroll
      for (int j = 0; j < 4; ++j) {
        float v = acc[i][j][r];
        sm8[mloc*PROW + kperm(wn + j*16 + c16)] = f2fp8(v);
        sq += v*v;
      }
      sq += __shfl_xor(sq, 1, 64); sq += __shfl_xor(sq, 2, 64);
      sq += __shfl_xor(sq, 4, 64); sq += __shfl_xor(sq, 8, 64);
      if (c16 == 0) {
        int m = m0 + mloc;
        atomicAdd(&nsq[(size_t)(h*B_ + (m & 3))*S_ + (m >> 2)], sq);
      }
    }
  __syncthreads();
  // coalesced fp8 stores: 4 passes x (32 rows x 8 col-granules)
  const int cg = t & 7, rsub = t >> 3;
#pragma unroll
  for (int c = 0; c < 4; ++c) {
    int mloc = c*32 + rsub;
    int m = m0 + mloc, s = m >> 2, b = m & 3;
    uint4 val = *(const uint4*)(sm8 + mloc*PROW + cg*16);
    *(uint4*)(outp + ((size_t)(h*B_ + b)*S_ + s)*K_ + (n0 & (K_-1)) + cg*16) = val;
  }
}

// ---------------- QK^T (fp8, k-permuted): row sums l[q] + E=exp(dot) fp8 ----
// 128x64 block tile: each wave 64x32 -> acc[4][2] = 32 AGPRs (unified-file
// footprint ~100 regs/wave -> 4-5 waves/SIMD vs 3 with the 128x128 tile).
// hb-per-XCD swizzle; per hb: q in 2 halves of 8 tiles (1 MB wqa hot set),
// s sweeps outer within a half. 8192 blocks. LDS 24 KB.
__global__ void __launch_bounds__(256) k_qkA(const unsigned char* __restrict__ wqa,
    const unsigned char* __restrict__ wka, const float* __restrict__ nq,
    const float* __restrict__ nk, float* __restrict__ lrow,
    unsigned char* __restrict__ E) {
  __shared__ __align__(16) unsigned char smbuf[24576];
  unsigned char* smA = smbuf;                     // 16 KB: 128 x 128
  unsigned char* smB = smbuf + 16384;             // 8 KB: 64 x 128
  int l = blockIdx.x, x = l & 7, rblk = l >> 3;   // rblk 0..1023
  int hb = x*2 + (rblk >> 9);                     // 2 hb per XCD
  int r2 = rblk & 511;
  int qh = r2 >> 8;                               // q half (8 q-tiles each)
  int rem = r2 & 255;
  int s0 = (rem >> 3)*64;                         // 32 s-tiles, outer
  int q0 = (qh*8 + (rem & 7))*128;                // q inner (reuses wka tile)
  const unsigned char* A  = wqa + (size_t)hb*S_*K_ + (size_t)q0*K_;
  const unsigned char* Bm = wka + (size_t)hb*S_*K_ + (size_t)s0*K_;
  const int t = threadIdx.x, wave = t>>6, lane = t&63;
  const int wm = (wave>>1)*64, wn = (wave&1)*32, quad = lane>>4, c16 = lane&15;
  f32x4 acc[4][2];
#pragma unroll
  for (int i = 0; i < 4; ++i)
#pragma unroll
    for (int j = 0; j < 2; ++j) acc[i][j] = f32x4{0.f,0.f,0.f,0.f};

  for (int kc = 0; kc < K_; kc += 128) {
    __syncthreads();
#pragma unroll
    for (int it = 0; it < 4; ++it) {              // A: 128 rows
      int c   = it*256 + t;
      int row = c >> 3;
      int g   = (c & 7) ^ (row & 7);
      gld_lds16(A + (size_t)row*K_ + kc + g*16, smA + (size_t)(it*256 + wave*64)*16);
    }
#pragma unroll
    for (int it = 0; it < 2; ++it) {              // B: 64 rows
      int c   = it*256 + t;
      int row = c >> 3;
      int g   = (c & 7) ^ (row & 7);
      gld_lds16(Bm + (size_t)row*K_ + kc + g*16, smB + (size_t)(it*256 + wave*64)*16);
    }
    asm volatile("s_waitcnt vmcnt(0)" ::: "memory");
    __syncthreads();
#pragma unroll
    for (int j2 = 0; j2 < 2; ++j2) {
      uint4 a4[4], b4[2];
#pragma unroll
      for (int i = 0; i < 4; ++i) {
        int ra = wm + i*16 + c16;
        a4[i] = *(const uint4*)(smA + ra*128 + (((j2*4 + quad) ^ (ra & 7)))*16);
      }
#pragma unroll
      for (int j = 0; j < 2; ++j) {
        int rb = wn + j*16 + c16;
        b4[j] = *(const uint4*)(smB + rb*128 + (((j2*4 + quad) ^ (rb & 7)))*16);
      }
#pragma unroll
      for (int hh = 0; hh < 2; ++hh)
#pragma unroll
        for (int i = 0; i < 4; ++i)
#pragma unroll
          for (int j = 0; j < 2; ++j)
            acc[i][j] = __builtin_amdgcn_mfma_f32_16x16x32_fp8_fp8(
                ((const long*)&a4[i])[hh], ((const long*)&b4[j])[hh],
                acc[i][j], 0, 0, 0);
    }
  }

  float rk2[2];
#pragma unroll
  for (int j = 0; j < 2; ++j)
    rk2[j] = rsqrtf(nk[(size_t)hb*S_ + s0 + wn + j*16 + c16]);
  unsigned char* sm8 = smbuf;
  __syncthreads();          // staging done; reuse sm as fp8 E tile (10 KB)
#pragma unroll
  for (int i = 0; i < 4; ++i)
#pragma unroll
    for (int r = 0; r < 4; ++r) {
      int qloc = wm + i*16 + quad*4 + r;
      float rq = rsqrtf(nq[(size_t)hb*S_ + q0 + qloc]);
      float rs = 0.f;
#pragma unroll
      for (int j = 0; j < 2; ++j) {
        float e = __expf(acc[i][j][r] * rq * rk2[j]);
        rs += e;
        sm8[qloc*EROW + wn + j*16 + c16] = f2fp8(e);
      }
      rs += __shfl_xor(rs, 1, 64); rs += __shfl_xor(rs, 2, 64);
      rs += __shfl_xor(rs, 4, 64); rs += __shfl_xor(rs, 8, 64);
      if (c16 == 0) atomicAdd(&lrow[(size_t)hb*S_ + q0 + qloc], rs);
    }
  __syncthreads();
  const int cg = t & 3, rsub = t >> 2;            // 4 granules x 64 rows
#pragma unroll
  for (int c = 0; c < 2; ++c) {
    int qloc = c*64 + rsub;
    uint4 val = *(const uint4*)(sm8 + qloc*EROW + cg*16);
    *(uint4*)(E + ((size_t)hb*S_ + q0 + qloc)*S_ + s0 + cg*16) = val;
  }
}

// ---------------- colsum from materialized fp8 E (vectorized) ---------------
__global__ void __launch_bounds__(256) k_colsumE(const unsigned char* __restrict__ E,
    const float* __restrict__ lrow, float* __restrict__ colsum,
    float* __restrict__ p0) {
  __shared__ float il[128];
  int hb = blockIdx.x, qc = blockIdx.y;   // grid (HB_, 16): 128 q rows/blk
  int t  = threadIdx.x;
  if (t < 128) il[t] = 1.f / lrow[(size_t)hb*S_ + qc*128 + t];
  __syncthreads();
  const unsigned char* Eb = E + (size_t)hb*S_*S_ + (size_t)(qc*128)*S_ + t*8;
  float acc8[8] = {0,0,0,0,0,0,0,0};
  for (int qi = 0; qi < 128; ++qi) {
    uint2 u = *(const uint2*)(Eb + (size_t)qi*S_);
    float w = il[qi];
    f32x2 v01 = __builtin_amdgcn_cvt_pk_f32_fp8(u.x, false);
    f32x2 v23 = __builtin_amdgcn_cvt_pk_f32_fp8(u.x, true);
    f32x2 v45 = __builtin_amdgcn_cvt_pk_f32_fp8(u.y, false);
    f32x2 v67 = __builtin_amdgcn_cvt_pk_f32_fp8(u.y, true);
    float v8[8] = {v01.x, v01.y, v23.x, v23.y, v45.x, v45.y, v67.x, v67.y};
#pragma unroll
    for (int k = 0; k < 8; ++k) acc8[k] += v8[k] * w;
    if (qc == 0 && qi == 0) {
#pragma unroll
      for (int k = 0; k < 8; ++k) p0[(size_t)hb*S_ + t*8 + k] = v8[k] * w;
    }
  }
#pragma unroll
  for (int k = 0; k < 8; ++k)
    atomicAdd(&colsum[(size_t)hb*S_ + t*8 + k], acc8[k]);
}

// ---------------- mid0: c[hb][d] = sum_s aff0[s]*kv[s,b,d]  (partial, atomic)
__global__ void __launch_bounds__(256) k_mid0(const float* __restrict__ p0,
    const float* __restrict__ colsum, const float* __restrict__ kv,
    float* __restrict__ cbuf) {
  __shared__ float aff[128];
  int hb = blockIdx.x, sc = blockIdx.y;
  int b = hb & 3;
  int t = threadIdx.x;
  if (t < 128) {
    int s = sc*128 + t;
    aff[t] = p0[(size_t)hb*S_ + s] / (1e-9f + colsum[(size_t)hb*S_ + s]);
  }
  __syncthreads();
  float acc = 0.f;
#pragma unroll 4
  for (int i = 0; i < 128; ++i) {
    int s = sc*128 + i;
    acc += aff[i] * kv[((size_t)s*B_ + b)*D_ + t];
  }
  atomicAdd(&cbuf[hb*D_ + t], acc);
}

// ---------------- mid1a: o0 -> qmo -> ru  (grid HB_, wave-per-row) ----------
__global__ void __launch_bounds__(256) k_mid1a(const float* __restrict__ cbuf,
    const float* __restrict__ mem, const float* __restrict__ WV,
    const float* __restrict__ Wt, float* __restrict__ ruW) {
  __shared__ float cS[D_], qmo[D_];
  int hb = blockIdx.x, h = hb >> 2, b = hb & 3;
  int t = threadIdx.x, wave = t >> 6, lane = t & 63;
  cS[t] = cbuf[hb*D_ + t];
  __syncthreads();
  float4 cv = *(const float4*)(cS + lane*4);
  for (int rr = 0; rr < 64; ++rr) {
    int e = wave*64 + rr;
    float4 w = *(const float4*)(WV + ((size_t)h*D_ + e)*D_ + lane*4);
    float a = wave_red(cv.x*w.x + cv.y*w.y + cv.z*w.z + cv.w*w.w);
    if (lane == 0) qmo[e] = mem[(size_t)b*D_ + e] - a;
  }
  __syncthreads();
  float4 qv = *(const float4*)(qmo + lane*4);
  for (int rr = 0; rr < 64; ++rr) {
    int e = wave*64 + rr;
    float4 w = *(const float4*)(Wt + ((size_t)h*D_ + e)*D_ + lane*4);
    float a = wave_red(qv.x*w.x + qv.y*w.y + qv.z*w.z + qv.w*w.w);
    if (lane == 0) ruW[hb*D_ + e] = fmaxf(a, 0.f);
  }
}

// ---------------- mid1b: hmid (grid HB_ x 8, wave-per-row) ------------------
__global__ void __launch_bounds__(256) k_mid1b(const float* __restrict__ ruW,
    const float* __restrict__ e1w, const float* __restrict__ e1b,
    float* __restrict__ hmW) {
  __shared__ float ru[D_];
  int hb = blockIdx.x, kc = blockIdx.y, h = hb >> 2;
  int t = threadIdx.x, wave = t >> 6, lane = t & 63;
  ru[t] = ruW[hb*D_ + t];
  __syncthreads();
  float4 rv = *(const float4*)(ru + lane*4);
  for (int rr = 0; rr < 32; ++rr) {
    int k = kc*128 + wave*32 + rr;
    float4 w = *(const float4*)(e1w + ((size_t)h*K_ + k)*D_ + lane*4);
    float a = wave_red(rv.x*w.x + rv.y*w.y + rv.z*w.z + rv.w*w.w);
    if (lane == 0) hmW[hb*K_ + k] = fmaxf(a + e1b[(size_t)h*K_ + k], 0.f);
  }
}

// ---------------- mid1c: s2 (grid HB_ x 8, wave-per-row) --------------------
__global__ void __launch_bounds__(256) k_mid1c(const float* __restrict__ hmW,
    const float* __restrict__ e2w, const float* __restrict__ e2b,
    float* __restrict__ s2W) {
  __shared__ float hm[K_];
  int hb = blockIdx.x, dc = blockIdx.y, h = hb >> 2;
  int t = threadIdx.x, wave = t >> 6, lane = t & 63;
  for (int k = t; k < K_; k += 256) hm[k] = hmW[hb*K_ + k];
  __syncthreads();
  for (int rr = 0; rr < 8; ++rr) {
    int d = dc*32 + wave*8 + rr;
    const float* row = e2w + ((size_t)h*D_ + d)*K_;
    float a = 0.f;
#pragma unroll
    for (int p = 0; p < 4; ++p) {
      float4 w = *(const float4*)(row + (p*64 + lane)*4);
      float4 hv = *(const float4*)(hm + (p*64 + lane)*4);
      a += w.x*hv.x + w.y*hv.y + w.z*hv.z + w.w*hv.w;
    }
    a = wave_red(a);
    if (lane == 0) s2W[hb*D_ + d] = a + e2b[(size_t)h*D_ + d];
  }
}

// ---------------- mid1d: LN(ru + s2) -> xh0 (grid HB_) ----------------------
__global__ void __launch_bounds__(256) k_mid1d(const float* __restrict__ ruW,
    const float* __restrict__ s2W, const float* __restrict__ eg,
    const float* __restrict__ ebias, float* __restrict__ xh0) {
  __shared__ float red[4];
  int hb = blockIdx.x, h = hb >> 2;
  int t = threadIdx.x;
  float tv = ruW[hb*D_ + t] + s2W[hb*D_ + t];
  float mean = blk_sum256(tv, red) * (1.f/D_);
  float dv = tv - mean;
  float var = blk_sum256(dv*dv, red) * (1.f/D_);
  xh0[hb*D_ + t] = dv * rsqrtf(var + 1e-5f) * eg[(size_t)h*D_ + t] + ebias[(size_t)h*D_ + t];
}

// ---------------- mid2: srcc2 (grid B_ x 8, wave-per-row) -------------------
__global__ void __launch_bounds__(256) k_mid2(const float* __restrict__ xh0,
    const float* __restrict__ Wout, float* __restrict__ srcc2) {
  __shared__ float cat[NH_*D_];
  int b = blockIdx.x, dc = blockIdx.y;
  int t = threadIdx.x, wave = t >> 6, lane = t & 63;
  for (int n = t; n < NH_*D_; n += 256)
    cat[n] = xh0[((size_t)(n >> 8)*B_ + b)*D_ + (n & 255)];
  __syncthreads();
  for (int rr = 0; rr < 8; ++rr) {
    int d = dc*32 + wave*8 + rr;
    const float* row = Wout + (size_t)d*(NH_*D_);
    float a = 0.f;
#pragma unroll
    for (int p = 0; p < 4; ++p) {
      float4 w = *(const float4*)(row + (p*64 + lane)*4);
      float4 cv = *(const float4*)(cat + (p*64 + lane)*4);
      a += w.x*cv.x + w.y*cv.y + w.z*cv.z + w.w*cv.w;
    }
    a = wave_red(a);
    if (lane == 0) srcc2[b*D_ + d] = a;
  }
}

// ---------------- F1: x = LN(memory + srcc2) -> fp32 + bf16 -----------------
__global__ void __launch_bounds__(256) k_f1(const float* __restrict__ mem,
    const float* __restrict__ srcc2, const float* __restrict__ g,
    const float* __restrict__ bb, float* __restrict__ xf,
    unsigned short* __restrict__ xb) {
  __shared__ float red[4];
  int m = blockIdx.x, t = threadIdx.x;
  float v = mem[(size_t)m*D_ + t] + srcc2[(m & 3)*D_ + t];
  float mean = blk_sum256(v, red) * (1.f/D_);
  float d = v - mean;
  float var = blk_sum256(d*d, red) * (1.f/D_);
  float y = d * rsqrtf(var + 1e-5f) * g[t] + bb[t];
  xf[(size_t)m*D_ + t] = y;
  xb[(size_t)m*D_ + t] = f2bf(y);
}

// ---------------- F2: h1 = relu(x @ l1w^T + l1b)  bf16 (XCD-swizzled) -------
__global__ void __launch_bounds__(256) k_f2(const unsigned short* __restrict__ xb,
    const unsigned short* __restrict__ l1wb, const float* __restrict__ l1b,
    unsigned short* __restrict__ h1) {
  __shared__ __align__(16) unsigned short sm[128*LDSROW];
  int l = blockIdx.x;
  int n0 = (l & 7)*128, m0 = (l >> 3)*128;
  f32x4 acc[4][4];
#pragma unroll
  for (int i = 0; i < 4; ++i)
#pragma unroll
    for (int j = 0; j < 4; ++j) acc[i][j] = f32x4{0.f,0.f,0.f,0.f};
  gemm_kloop(xb + (size_t)m0*D_, l1wb + (size_t)n0*D_, D_, D_, D_, sm, sm + 128*64, acc);
  const int t = threadIdx.x, wave = t>>6, lane = t&63;
  const int wm = (wave>>1)*64, wn = (wave&1)*64, quad = lane>>4, c16 = lane&15;
  __syncthreads();
#pragma unroll
  for (int i = 0; i < 4; ++i)
#pragma unroll
    for (int r = 0; r < 4; ++r) {
      int mloc = wm + i*16 + quad*4 + r;
#pragma unroll
      for (int j = 0; j < 4; ++j) {
        int n = n0 + wn + j*16 + c16;
        sm[mloc*LDSROW + wn + j*16 + c16] = f2bf(fmaxf(acc[i][j][r] + l1b[n], 0.f));
      }
    }
  __syncthreads();
  const int col8 = (t & 15)*8, rsub = t >> 4;
#pragma unroll
  for (int c = 0; c < 8; ++c) {
    int mloc = c*16 + rsub;
    uint4 val = *(const uint4*)(sm + mloc*LDSROW + col8);
    *(uint4*)(h1 + (size_t)(m0 + mloc)*FF_ + n0 + col8) = val;
  }
}

// ---------------- F3: split-K 2x into two buffers (no atomics) --------------
__global__ void __launch_bounds__(256) k_f3(const unsigned short* __restrict__ h1,
    const unsigned short* __restrict__ l2wb, float* __restrict__ yfa,
    float* __restrict__ yfb) {
  __shared__ __align__(16) unsigned short smA[128*64], smB[128*64];
  int l = blockIdx.x;                 // 256 blocks: z = K-half, n (2), m (64)
  int z = l & 1, n0 = ((l >> 1) & 1)*128, m0 = (l >> 2)*128;
  float* dst = z ? yfb : yfa;
  f32x4 acc[4][4];
#pragma unroll
  for (int i = 0; i < 4; ++i)
#pragma unroll
    for (int j = 0; j < 4; ++j) acc[i][j] = f32x4{0.f,0.f,0.f,0.f};
  gemm_kloop(h1 + (size_t)m0*FF_ + z*512, l2wb + (size_t)n0*FF_ + z*512,
             FF_, FF_, 512, smA, smB, acc);
  const int t = threadIdx.x, wave = t>>6, lane = t&63;
  const int wm = (wave>>1)*64, wn = (wave&1)*64, quad = lane>>4, c16 = lane&15;
#pragma unroll
  for (int i = 0; i < 4; ++i)
#pragma unroll
    for (int r = 0; r < 4; ++r) {
      int m = m0 + wm + i*16 + quad*4 + r;
#pragma unroll
      for (int j = 0; j < 4; ++j) {
        int n = n0 + wn + j*16 + c16;
        dst[(size_t)m*D_ + n] = acc[i][j][r];
      }
    }
}

// ---------------- F4: out = LN(yfa + yfb + l2b + x) -------------------------
__global__ void __launch_bounds__(256) k_f4(const float* __restrict__ yfa,
    const float* __restrict__ yfb, const float* __restrict__ l2b,
    const float* __restrict__ xf, const float* __restrict__ g,
    const float* __restrict__ bb, float* __restrict__ out) {
  __shared__ float red[4];
  int m = blockIdx.x, t = threadIdx.x;
  size_t idx = (size_t)m*D_ + t;
  float v = yfa[idx] + yfb[idx] + l2b[t] + xf[idx];
  float mean = blk_sum256(v, red) * (1.f/D_);
  float d = v - mean;
  float var = blk_sum256(d*d, red) * (1.f/D_);
  out[idx] = d * rsqrtf(var + 1e-5f) * g[t] + bb[t];
}

// ---------------- workspace layout (bytes) ----------------------------------
constexpr size_t SZ_ACT  = (size_t)HB_*S_*K_;                   // 32 MiB (fp8)
constexpr size_t OFF_WQA = 0;
constexpr size_t OFF_WKA = OFF_WQA + SZ_ACT;
constexpr size_t OFF_KVB = OFF_WKA + SZ_ACT;
constexpr size_t OFF_QB  = OFF_KVB + (size_t)M_*D_*2;
constexpr size_t OFF_WKW = OFF_QB  + (size_t)M_*D_*2;
constexpr size_t OFF_WQW = OFF_WKW + (size_t)NH_*K_*D_*2;
constexpr size_t OFF_L1W = OFF_WQW + (size_t)NH_*K_*D_*2;
constexpr size_t OFF_L2W = OFF_L1W + (size_t)FF_*D_*2;
constexpr size_t OFF_XB  = OFF_L2W + (size_t)D_*FF_*2;
constexpr size_t OFF_H1  = OFF_XB  + (size_t)M_*D_*2;
constexpr size_t OFF_XF  = OFF_H1  + (size_t)M_*FF_*2;
constexpr size_t OFF_YF0 = OFF_XF  + (size_t)M_*D_*4;
constexpr size_t OFF_YF1 = OFF_YF0 + (size_t)M_*D_*4;
constexpr size_t OFF_NQ  = OFF_YF1 + (size_t)M_*D_*4;           // zero region
constexpr size_t OFF_NK  = OFF_NQ + (size_t)HB_*S_*4;
constexpr size_t OFF_L   = OFF_NK + (size_t)HB_*S_*4;
constexpr size_t OFF_CS  = OFF_L  + (size_t)HB_*S_*4;
constexpr size_t OFF_CB  = OFF_CS + (size_t)HB_*S_*4;
constexpr size_t ZERO_BYTES = (size_t)HB_*S_*4*4 + (size_t)HB_*D_*4;
constexpr size_t OFF_P0  = OFF_CB + (size_t)HB_*D_*4;
constexpr size_t OFF_XH0 = OFF_P0 + (size_t)HB_*S_*4;
constexpr size_t OFF_SC2 = OFF_XH0 + (size_t)HB_*D_*4;
constexpr size_t OFF_RU  = OFF_SC2 + (size_t)B_*D_*4;
constexpr size_t OFF_HM  = OFF_RU  + (size_t)HB_*D_*4;
constexpr size_t OFF_S2  = OFF_HM  + (size_t)HB_*K_*4;
constexpr size_t OFF_E   = OFF_S2  + (size_t)HB_*D_*4;
constexpr size_t SZ_E    = (size_t)HB_*S_*S_;                   // 64 MiB (fp8)
constexpr size_t NEED_ALL = OFF_E + SZ_E;                       // ~194 MiB

extern "C" void kernel_launch(void* const* d_in, const int* in_sizes, int n_in,
                              void* d_out, int out_size, void* d_ws, size_t ws_size,
                              hipStream_t stream) {
  (void)in_sizes; (void)out_size;
  if (n_in < 21) return;
  const float* srcc = (const float*)d_in[0];
  const float* mem  = (const float*)d_in[1];
  const float* WK   = (const float*)d_in[2];
  const float* WQ   = (const float*)d_in[3];
  const float* WV   = (const float*)d_in[4];
  const float* Wt   = (const float*)d_in[5];
  const float* e1w  = (const float*)d_in[6];
  const float* e1b  = (const float*)d_in[7];
  const float* e2w  = (const float*)d_in[8];
  const float* e2b  = (const float*)d_in[9];
  const float* eg   = (const float*)d_in[10];
  const float* eb   = (const float*)d_in[11];
  const float* Wout = (const float*)d_in[12];
  const float* l1w  = (const float*)d_in[13];
  const float* l1b  = (const float*)d_in[14];
  const float* l2w  = (const float*)d_in[15];
  const float* l2b  = (const float*)d_in[16];
  const float* n1g  = (const float*)d_in[17];
  const float* n1b  = (const float*)d_in[18];
  const float* n3g  = (const float*)d_in[19];
  const float* n3b  = (const float*)d_in[20];

  char* ws = (char*)d_ws;
  if (ws_size < NEED_ALL) {
    fprintf(stderr, "kernel_launch: ws_size=%zu < required %zu bytes — aborting\n",
            ws_size, NEED_ALL);
    return;
  }

  unsigned char*  wqa  = (unsigned char*)(ws + OFF_WQA);
  unsigned char*  wka  = (unsigned char*)(ws + OFF_WKA);
  unsigned short* kvb  = (unsigned short*)(ws + OFF_KVB);
  unsigned short* qb   = (unsigned short*)(ws + OFF_QB);
  unsigned short* wkw  = (unsigned short*)(ws + OFF_WKW);
  unsigned short* wqw  = (unsigned short*)(ws + OFF_WQW);
  unsigned short* l1wb = (unsigned short*)(ws + OFF_L1W);
  unsigned short* l2wb = (unsigned short*)(ws + OFF_L2W);
  unsigned short* xb   = (unsigned short*)(ws + OFF_XB);
  unsigned short* h1   = (unsigned short*)(ws + OFF_H1);
  float* xf    = (float*)(ws + OFF_XF);
  float* yf0   = (float*)(ws + OFF_YF0);
  float* yf1   = (float*)(ws + OFF_YF1);
  float* nq    = (float*)(ws + OFF_NQ);
  float* nk    = (float*)(ws + OFF_NK);
  float* lrow  = (float*)(ws + OFF_L);
  float* cs    = (float*)(ws + OFF_CS);
  float* cbuf  = (float*)(ws + OFF_CB);
  float* p0    = (float*)(ws + OFF_P0);
  float* xh0   = (float*)(ws + OFF_XH0);
  float* sc2   = (float*)(ws + OFF_SC2);
  float* ruW   = (float*)(ws + OFF_RU);
  float* hmW   = (float*)(ws + OFF_HM);
  float* s2W   = (float*)(ws + OFF_S2);
  unsigned char* E = (unsigned char*)(ws + OFF_E);

  // fp32 -> bf16 conversions + zero-fill of atomic buffers, one launch
  int zfloats = (int)(ZERO_BYTES/4);
  int zblocks = (zfloats + 1023)/1024;
  k_cvt6z<<<6656 + zblocks, 256, 0, stream>>>(srcc, kvb, mem, qb, WK, wkw,
                                              WQ, wqw, l1w, l1wb, l2w, l2wb,
                                              nq, zfloats);

  // both projections (bf16 GEMM -> fp8 out, k-permuted) + row norm^2
  k_proj2<<<4096, 256, 0, stream>>>(kvb, wkw, nk, wka, qb, wqw, nq, wqa);

  // QK^T fp8 (128x64 tile, fp8 E, hb-per-XCD locality) + weighted colsum
  k_qkA<<<8192, 256, 0, stream>>>(wqa, wka, nq, nk, lrow, E);
  k_colsumE<<<dim3(HB_, 16), 256, 0, stream>>>(E, lrow, cs, p0);

  // q=0 tail of the RMA block
  k_mid0<<<dim3(HB_, S_/128), 256, 0, stream>>>(p0, cs, srcc, cbuf);
  k_mid1a<<<HB_, 256, 0, stream>>>(cbuf, mem, WV, Wt, ruW);
  k_mid1b<<<dim3(HB_, 8), 256, 0, stream>>>(ruW, e1w, e1b, hmW);
  k_mid1c<<<dim3(HB_, 8), 256, 0, stream>>>(hmW, e2w, e2b, s2W);
  k_mid1d<<<HB_, 256, 0, stream>>>(ruW, s2W, eg, eb, xh0);
  k_mid2<<<dim3(B_, 8), 256, 0, stream>>>(xh0, Wout, sc2);

  // decoder FFN
  k_f1<<<M_, 256, 0, stream>>>(mem, sc2, n1g, n1b, xf, xb);
  k_f2<<<512, 256, 0, stream>>>(xb, l1wb, l1b, h1);
  k_f3<<<256, 256, 0, stream>>>(h1, l2wb, yf0, yf1);
  k_f4<<<M_, 256, 0, stream>>>(yf0, yf1, l2b, xf, n3g, n3b, (float*)d_out);
}

// Round 12
// 557.630 us; speedup vs baseline: 1.0848x; 1.0533x over previous
//
#include <hip/hip_runtime.h>
#include <stdint.h>
#include <stdio.h>

#define S_  2048
#define B_  4
#define D_  256
#define NH_ 4
#define K_  1024
#define FF_ 1024
#define M_  (S_*B_)      // 8192 rows (s,b)
#define HB_ (NH_*B_)     // 16 (h,b) pairs

// bf16 LDS tile row stride (shorts): 128 data + 8 pad (272 B rows).
#define LDSROW 136
// fp8 LDS tile row stride (bytes): 128 data + 16 pad, 16B-aligned.
#define PROW 144

typedef float  f32x4  __attribute__((ext_vector_type(4)));
typedef float  f32x2  __attribute__((ext_vector_type(2)));
typedef __bf16 bf16x8 __attribute__((ext_vector_type(8)));

__device__ __forceinline__ float bf2f(unsigned short u) {
  union { unsigned int i; float f; } v; v.i = ((unsigned int)u) << 16; return v.f;
}
__device__ __forceinline__ unsigned short f2bf(float f) {
  union { float f; unsigned int i; } v; v.f = f;
  unsigned int r = v.i + 0x7fffu + ((v.i >> 16) & 1u);
  return (unsigned short)(r >> 16);
}
__device__ __forceinline__ unsigned char f2fp8(float f) {
  return (unsigned char)(__builtin_amdgcn_cvt_pk_fp8_f32(f, f, 0, false) & 0xff);
}

// k-permutation within each 128-wide K window: any dot product is invariant
// when the SAME permutation is applied to both operands; makes each lane's
// fp8 MFMA fragments for ks=2j,2j+1 16B-contiguous -> conflict-free
// ds_read_b128. ALL fp8 GEMM inputs are stored k-permuted.
__device__ __forceinline__ int kperm(int k) {
  int ks = k >> 5, quad = (k >> 3) & 3, b = k & 7;
  return ((ks >> 1) << 6) + (quad << 4) + ((ks & 1) << 3) + b;
}

__device__ __forceinline__ void gld_lds16(const void* g, void* l) {
  __builtin_amdgcn_global_load_lds(
      (__attribute__((address_space(1))) void*)(uintptr_t)g,
      (__attribute__((address_space(3))) void*)(uintptr_t)l, 16, 0, 0);
}

// ---------------- 128x128 bf16 GEMM-BT K-loop (m97 pattern) ----------------
__device__ __forceinline__ void gemm_kloop(
    const unsigned short* __restrict__ Ag, const unsigned short* __restrict__ Bg,
    int lda, int ldb, int kdim,
    unsigned short* __restrict__ smA, unsigned short* __restrict__ smB,
    f32x4 acc[4][4])
{
  const int t    = threadIdx.x;
  const int wave = t >> 6;
  const int lane = t & 63;
  const int wm   = (wave >> 1) << 6;
  const int wn   = (wave & 1) << 6;
  const int c16  = lane & 15;
  const int quad = lane >> 4;

  for (int kc = 0; kc < kdim; kc += 64) {
    __syncthreads();
#pragma unroll
    for (int it = 0; it < 4; ++it) {
      int c   = it*256 + t;
      int row = c >> 3;
      int g   = (c & 7) ^ (row & 7);
      gld_lds16(Ag + (size_t)row*lda + kc + g*8, smA + (size_t)(it*256 + wave*64)*8);
      gld_lds16(Bg + (size_t)row*ldb + kc + g*8, smB + (size_t)(it*256 + wave*64)*8);
    }
    asm volatile("s_waitcnt vmcnt(0)" ::: "memory");
    __syncthreads();
#pragma unroll
    for (int ks = 0; ks < 2; ++ks) {
      bf16x8 av[4], bv[4];
#pragma unroll
      for (int i = 0; i < 4; ++i) {
        int ra = wm + i*16 + c16;
        av[i] = *(const bf16x8*)(smA + ra*64 + (((ks*4 + quad) ^ (ra & 7)))*8);
        int rb = wn + i*16 + c16;
        bv[i] = *(const bf16x8*)(smB + rb*64 + (((ks*4 + quad) ^ (rb & 7)))*8);
      }
#pragma unroll
      for (int i = 0; i < 4; ++i)
#pragma unroll
        for (int j = 0; j < 4; ++j)
          acc[i][j] = __builtin_amdgcn_mfma_f32_16x16x32_bf16(av[i], bv[j], acc[i][j], 0, 0, 0);
    }
  }
}

// ---------------- 128x128 fp8 GEMM-BT K-loop (BK=128, r8-proven) ------------
__device__ __forceinline__ void gemm_kloop_fp8(
    const unsigned char* __restrict__ Ag, const unsigned char* __restrict__ Bg,
    int lda, int ldb, int kdim,
    unsigned char* __restrict__ smA, unsigned char* __restrict__ smB,
    f32x4 acc[4][4])
{
  const int t    = threadIdx.x;
  const int wave = t >> 6;
  const int lane = t & 63;
  const int wm   = (wave >> 1) << 6;
  const int wn   = (wave & 1) << 6;
  const int c16  = lane & 15;
  const int quad = lane >> 4;

  for (int kc = 0; kc < kdim; kc += 128) {
    __syncthreads();
#pragma unroll
    for (int it = 0; it < 4; ++it) {
      int c   = it*256 + t;
      int row = c >> 3;
      int g   = (c & 7) ^ (row & 7);
      gld_lds16(Ag + (size_t)row*lda + kc + g*16, smA + (size_t)(it*256 + wave*64)*16);
      gld_lds16(Bg + (size_t)row*ldb + kc + g*16, smB + (size_t)(it*256 + wave*64)*16);
    }
    asm volatile("s_waitcnt vmcnt(0)" ::: "memory");
    __syncthreads();
#pragma unroll
    for (int j2 = 0; j2 < 2; ++j2) {
      uint4 a4[4], b4[4];
#pragma unroll
      for (int i = 0; i < 4; ++i) {
        int ra = wm + i*16 + c16;
        a4[i] = *(const uint4*)(smA + ra*128 + (((j2*4 + quad) ^ (ra & 7)))*16);
        int rb = wn + i*16 + c16;
        b4[i] = *(const uint4*)(smB + rb*128 + (((j2*4 + quad) ^ (rb & 7)))*16);
      }
#pragma unroll
      for (int hh = 0; hh < 2; ++hh)
#pragma unroll
        for (int i = 0; i < 4; ++i)
#pragma unroll
          for (int j = 0; j < 4; ++j)
            acc[i][j] = __builtin_amdgcn_mfma_f32_16x16x32_fp8_fp8(
                ((const long*)&a4[i])[hh], ((const long*)&b4[j])[hh],
                acc[i][j], 0, 0, 0);
    }
  }
}

__device__ __forceinline__ float blk_sum256(float v, float* red) {
#pragma unroll
  for (int o = 32; o; o >>= 1) v += __shfl_xor(v, o, 64);
  __syncthreads();
  if ((threadIdx.x & 63) == 0) red[threadIdx.x >> 6] = v;
  __syncthreads();
  return red[0] + red[1] + red[2] + red[3];
}

__device__ __forceinline__ float wave_red(float a) {
#pragma unroll
  for (int o = 1; o < 64; o <<= 1) a += __shfl_xor(a, o, 64);
  return a;
}

// ------ fused convert: 4x fp32->fp8(k-perm) + 2x fp32->bf16 + zero tail -----
// fp8 dests (attention side): srcc, mem, WK, WQ. bf16 dests (FFN): l1w, l2w.
__global__ void __launch_bounds__(256) k_cvtmix(
    const float* __restrict__ s0, unsigned char* __restrict__ d0,
    const float* __restrict__ s1, unsigned char* __restrict__ d1,
    const float* __restrict__ s2, unsigned char* __restrict__ d2,
    const float* __restrict__ s3, unsigned char* __restrict__ d3,
    const float* __restrict__ s4, unsigned short* __restrict__ d4,
    const float* __restrict__ s5, unsigned short* __restrict__ d5,
    float* __restrict__ zbase, int zfloats) {
  int b = blockIdx.x;
  if (b >= 6656) {                       // zero-fill tail blocks
    int i = ((b - 6656)*256 + threadIdx.x)*4;
    if (i + 3 < zfloats) *(float4*)(zbase + i) = float4{0.f,0.f,0.f,0.f};
    return;
  }
  if (b >= 6144) {                       // bf16 region: l1w (256) + l2w (256)
    const float* src; unsigned short* dst; int base;
    if (b < 6400) { src = s4; dst = d4; base = b - 6144; }
    else          { src = s5; dst = d5; base = b - 6400; }
    int i = (base*256 + threadIdx.x)*4;
    float4 v = *(const float4*)(src + i);
    ushort4 o;
    o.x = f2bf(v.x); o.y = f2bf(v.y); o.z = f2bf(v.z); o.w = f2bf(v.w);
    *(ushort4*)(dst + i) = o;
    return;
  }
  const float* src; unsigned char* dst; int base;
  if      (b < 2048) { src = s0; dst = d0; base = b; }
  else if (b < 4096) { src = s1; dst = d1; base = b - 2048; }
  else if (b < 5120) { src = s2; dst = d2; base = b - 4096; }
  else               { src = s3; dst = d3; base = b - 5120; }
  int i = (base*256 + threadIdx.x)*4;
  float4 v = *(const float4*)(src + i);
  uchar4 o;
  o.x = f2fp8(v.x); o.y = f2fp8(v.y); o.z = f2fp8(v.z); o.w = f2fp8(v.w);
  int dsto = (i & ~127) + kperm(i & 127);   // 4-aligned (low 2 bits preserved)
  *(uchar4*)(dst + dsto) = o;
}

// ---------------- projections (both in one launch): C = X * W^T -------------
// fp8 k-permuted inputs (K=D=256, 2 BK=128 trips); out fp8 k-permuted;
// nsq += sum_k C^2 (fp32, from the same accumulator the output quantizes).
__global__ void __launch_bounds__(256) k_proj2(
    const unsigned char* __restrict__ X0, const unsigned char* __restrict__ W0,
    float* __restrict__ n0p, unsigned char* __restrict__ o0p,
    const unsigned char* __restrict__ X1, const unsigned char* __restrict__ W1,
    float* __restrict__ n1p, unsigned char* __restrict__ o1p) {
  __shared__ __align__(16) unsigned char smbuf[32768];
  unsigned char* smA = smbuf;
  unsigned char* smB = smbuf + 16384;
  int which = blockIdx.x >> 11;
  const unsigned char* X = which ? X1 : X0;
  const unsigned char* W = which ? W1 : W0;
  float* nsq = which ? n1p : n0p;
  unsigned char* outp = which ? o1p : o0p;
  int l = blockIdx.x & 2047, x = l & 7, rblk = l >> 3;
  int m0 = (rblk >> 2)*128;
  int n0 = (x*4 + (rblk & 3))*128;
  f32x4 acc[4][4];
#pragma unroll
  for (int i = 0; i < 4; ++i)
#pragma unroll
    for (int j = 0; j < 4; ++j) acc[i][j] = f32x4{0.f,0.f,0.f,0.f};
  gemm_kloop_fp8(X + (size_t)m0*D_, W + (size_t)n0*D_, D_, D_, D_, smA, smB, acc);
  const int t = threadIdx.x, wave = t>>6, lane = t&63;
  const int wm = (wave>>1)*64, wn = (wave&1)*64, quad = lane>>4, c16 = lane&15;
  const int h = n0 >> 10;
  unsigned char* sm8 = smbuf;
  __syncthreads();          // staging done; reuse sm as fp8 output tile (18 KB)
#pragma unroll
  for (int i = 0; i < 4; ++i)
#pragma unroll
    for (int r = 0; r < 4; ++r) {
      int mloc = wm + i*16 + quad*4 + r;
      float sq = 0.f;
#pragma unroll
      for (int j = 0; j < 4; ++j) {
        float v = acc[i][j][r];
        sm8[mloc*PROW + kperm(wn + j*16 + c16)] = f2fp8(v);
        sq += v*v;
      }
      sq += __shfl_xor(sq, 1, 64); sq += __shfl_xor(sq, 2, 64);
      sq += __shfl_xor(sq, 4, 64); sq += __shfl_xor(sq, 8, 64);
      if (c16 == 0) {
        int m = m0 + mloc;
        atomicAdd(&nsq[(size_t)(h*B_ + (m & 3))*S_ + (m >> 2)], sq);
      }
    }
  __syncthreads();
  const int cg = t & 7, rsub = t >> 3;
#pragma unroll
  for (int c = 0; c < 4; ++c) {
    int mloc = c*32 + rsub;
    int m = m0 + mloc, s = m >> 2, b = m & 3;
    uint4 val = *(const uint4*)(sm8 + mloc*PROW + cg*16);
    *(uint4*)(outp + ((size_t)(h*B_ + b)*S_ + s)*K_ + (n0 & (K_-1)) + cg*16) = val;
  }
}

// ---------------- QK^T (fp8, k-permuted): row sums l[q] + E=exp(dot) fp8 ----
// r8 128x128 tile; hb-per-XCD swizzle, s outer / q inner for L2 residency.
__global__ void __launch_bounds__(256) k_qkA(const unsigned char* __restrict__ wqa,
    const unsigned char* __restrict__ wka, const float* __restrict__ nq,
    const float* __restrict__ nk, float* __restrict__ lrow,
    unsigned char* __restrict__ E) {
  __shared__ __align__(16) unsigned char smbuf[32768];
  unsigned char* smA = smbuf;
  unsigned char* smB = smbuf + 16384;
  int l = blockIdx.x, x = l & 7, rblk = l >> 3;   // rblk 0..511
  int hb = x*2 + (rblk >> 8);                     // 2 hb per XCD
  int r2 = rblk & 255;
  int s0 = (r2 >> 4)*128;                         // s outer
  int q0 = (r2 & 15)*128;                         // q inner (reuses wka tile)
  const unsigned char* A  = wqa + (size_t)hb*S_*K_ + (size_t)q0*K_;
  const unsigned char* Bm = wka + (size_t)hb*S_*K_ + (size_t)s0*K_;
  const int t = threadIdx.x, wave = t>>6, lane = t&63;
  const int wm = (wave>>1)*64, wn = (wave&1)*64, quad = lane>>4, c16 = lane&15;
  f32x4 acc[4][4];
#pragma unroll
  for (int i = 0; i < 4; ++i)
#pragma unroll
    for (int j = 0; j < 4; ++j) acc[i][j] = f32x4{0.f,0.f,0.f,0.f};
  gemm_kloop_fp8(A, Bm, K_, K_, K_, smA, smB, acc);

  float rk4[4];
#pragma unroll
  for (int j = 0; j < 4; ++j)
    rk4[j] = rsqrtf(nk[(size_t)hb*S_ + s0 + wn + j*16 + c16]);
  unsigned char* sm8 = smbuf;
  __syncthreads();          // staging done; reuse sm as fp8 E tile (18 KB)
#pragma unroll
  for (int i = 0; i < 4; ++i)
#pragma unroll
    for (int r = 0; r < 4; ++r) {
      int qloc = wm + i*16 + quad*4 + r;
      float rq = rsqrtf(nq[(size_t)hb*S_ + q0 + qloc]);
      float rs = 0.f;
#pragma unroll
      for (int j = 0; j < 4; ++j) {
        float e = __expf(acc[i][j][r] * rq * rk4[j]);
        rs += e;
        sm8[qloc*PROW + wn + j*16 + c16] = f2fp8(e);
      }
      rs += __shfl_xor(rs, 1, 64); rs += __shfl_xor(rs, 2, 64);
      rs += __shfl_xor(rs, 4, 64); rs += __shfl_xor(rs, 8, 64);
      if (c16 == 0) atomicAdd(&lrow[(size_t)hb*S_ + q0 + qloc], rs);
    }
  __syncthreads();
  const int cg = t & 7, rsub = t >> 3;
#pragma unroll
  for (int c = 0; c < 4; ++c) {
    int qloc = c*32 + rsub;
    uint4 val = *(const uint4*)(sm8 + qloc*PROW + cg*16);
    *(uint4*)(E + ((size_t)hb*S_ + q0 + qloc)*S_ + s0 + cg*16) = val;
  }
}

// ---------------- colsum from materialized fp8 E (vectorized) ---------------
__global__ void __launch_bounds__(256) k_colsumE(const unsigned char* __restrict__ E,
    const float* __restrict__ lrow, float* __restrict__ colsum,
    float* __restrict__ p0) {
  __shared__ float il[128];
  int hb = blockIdx.x, qc = blockIdx.y;   // grid (HB_, 16): 128 q rows/blk
  int t  = threadIdx.x;
  if (t < 128) il[t] = 1.f / lrow[(size_t)hb*S_ + qc*128 + t];
  __syncthreads();
  const unsigned char* Eb = E + (size_t)hb*S_*S_ + (size_t)(qc*128)*S_ + t*8;
  float acc8[8] = {0,0,0,0,0,0,0,0};
  for (int qi = 0; qi < 128; ++qi) {
    uint2 u = *(const uint2*)(Eb + (size_t)qi*S_);
    float w = il[qi];
    f32x2 v01 = __builtin_amdgcn_cvt_pk_f32_fp8(u.x, false);
    f32x2 v23 = __builtin_amdgcn_cvt_pk_f32_fp8(u.x, true);
    f32x2 v45 = __builtin_amdgcn_cvt_pk_f32_fp8(u.y, false);
    f32x2 v67 = __builtin_amdgcn_cvt_pk_f32_fp8(u.y, true);
    float v8[8] = {v01.x, v01.y, v23.x, v23.y, v45.x, v45.y, v67.x, v67.y};
#pragma unroll
    for (int k = 0; k < 8; ++k) acc8[k] += v8[k] * w;
    if (qc == 0 && qi == 0) {
#pragma unroll
      for (int k = 0; k < 8; ++k) p0[(size_t)hb*S_ + t*8 + k] = v8[k] * w;
    }
  }
#pragma unroll
  for (int k = 0; k < 8; ++k)
    atomicAdd(&colsum[(size_t)hb*S_ + t*8 + k], acc8[k]);
}

// ---------------- mid0: c[hb][d] = sum_s aff0[s]*kv[s,b,d]  (partial, atomic)
__global__ void __launch_bounds__(256) k_mid0(const float* __restrict__ p0,
    const float* __restrict__ colsum, const float* __restrict__ kv,
    float* __restrict__ cbuf) {
  __shared__ float aff[128];
  int hb = blockIdx.x, sc = blockIdx.y;
  int b = hb & 3;
  int t = threadIdx.x;
  if (t < 128) {
    int s = sc*128 + t;
    aff[t] = p0[(size_t)hb*S_ + s] / (1e-9f + colsum[(size_t)hb*S_ + s]);
  }
  __syncthreads();
  float acc = 0.f;
#pragma unroll 4
  for (int i = 0; i < 128; ++i) {
    int s = sc*128 + i;
    acc += aff[i] * kv[((size_t)s*B_ + b)*D_ + t];
  }
  atomicAdd(&cbuf[hb*D_ + t], acc);
}

// ---------------- mid1a: o0 -> qmo -> ru  (grid HB_, wave-per-row) ----------
__global__ void __launch_bounds__(256) k_mid1a(const float* __restrict__ cbuf,
    const float* __restrict__ mem, const float* __restrict__ WV,
    const float* __restrict__ Wt, float* __restrict__ ruW) {
  __shared__ float cS[D_], qmo[D_];
  int hb = blockIdx.x, h = hb >> 2, b = hb & 3;
  int t = threadIdx.x, wave = t >> 6, lane = t & 63;
  cS[t] = cbuf[hb*D_ + t];
  __syncthreads();
  float4 cv = *(const float4*)(cS + lane*4);
  for (int rr = 0; rr < 64; ++rr) {
    int e = wave*64 + rr;
    float4 w = *(const float4*)(WV + ((size_t)h*D_ + e)*D_ + lane*4);
    float a = wave_red(cv.x*w.x + cv.y*w.y + cv.z*w.z + cv.w*w.w);
    if (lane == 0) qmo[e] = mem[(size_t)b*D_ + e] - a;
  }
  __syncthreads();
  float4 qv = *(const float4*)(qmo + lane*4);
  for (int rr = 0; rr < 64; ++rr) {
    int e = wave*64 + rr;
    float4 w = *(const float4*)(Wt + ((size_t)h*D_ + e)*D_ + lane*4);
    float a = wave_red(qv.x*w.x + qv.y*w.y + qv.z*w.z + qv.w*w.w);
    if (lane == 0) ruW[hb*D_ + e] = fmaxf(a, 0.f);
  }
}

// ---------------- mid1b: hmid (grid HB_ x 8, wave-per-row) ------------------
__global__ void __launch_bounds__(256) k_mid1b(const float* __restrict__ ruW,
    const float* __restrict__ e1w, const float* __restrict__ e1b,
    float* __restrict__ hmW) {
  __shared__ float ru[D_];
  int hb = blockIdx.x, kc = blockIdx.y, h = hb >> 2;
  int t = threadIdx.x, wave = t >> 6, lane = t & 63;
  ru[t] = ruW[hb*D_ + t];
  __syncthreads();
  float4 rv = *(const float4*)(ru + lane*4);
  for (int rr = 0; rr < 32; ++rr) {
    int k = kc*128 + wave*32 + rr;
    float4 w = *(const float4*)(e1w + ((size_t)h*K_ + k)*D_ + lane*4);
    float a = wave_red(rv.x*w.x + rv.y*w.y + rv.z*w.z + rv.w*w.w);
    if (lane == 0) hmW[hb*K_ + k] = fmaxf(a + e1b[(size_t)h*K_ + k], 0.f);
  }
}

// ---------------- mid1c: s2 (grid HB_ x 8, wave-per-row) --------------------
__global__ void __launch_bounds__(256) k_mid1c(const float* __restrict__ hmW,
    const float* __restrict__ e2w, const float* __restrict__ e2b,
    float* __restrict__ s2W) {
  __shared__ float hm[K_];
  int hb = blockIdx.x, dc = blockIdx.y, h = hb >> 2;
  int t = threadIdx.x, wave = t >> 6, lane = t & 63;
  for (int k = t; k < K_; k += 256) hm[k] = hmW[hb*K_ + k];
  __syncthreads();
  for (int rr = 0; rr < 8; ++rr) {
    int d = dc*32 + wave*8 + rr;
    const float* row = e2w + ((size_t)h*D_ + d)*K_;
    float a = 0.f;
#pragma unroll
    for (int p = 0; p < 4; ++p) {
      float4 w = *(const float4*)(row + (p*64 + lane)*4);
      float4 hv = *(const float4*)(hm + (p*64 + lane)*4);
      a += w.x*hv.x + w.y*hv.y + w.z*hv.z + w.w*hv.w;
    }
    a = wave_red(a);
    if (lane == 0) s2W[hb*D_ + d] = a + e2b[(size_t)h*D_ + d];
  }
}

// ---------------- mid1d: LN(ru + s2) -> xh0 (grid HB_) ----------------------
__global__ void __launch_bounds__(256) k_mid1d(const float* __restrict__ ruW,
    const float* __restrict__ s2W, const float* __restrict__ eg,
    const float* __restrict__ ebias, float* __restrict__ xh0) {
  __shared__ float red[4];
  int hb = blockIdx.x, h = hb >> 2;
  int t = threadIdx.x;
  float tv = ruW[hb*D_ + t] + s2W[hb*D_ + t];
  float mean = blk_sum256(tv, red) * (1.f/D_);
  float dv = tv - mean;
  float var = blk_sum256(dv*dv, red) * (1.f/D_);
  xh0[hb*D_ + t] = dv * rsqrtf(var + 1e-5f) * eg[(size_t)h*D_ + t] + ebias[(size_t)h*D_ + t];
}

// ---------------- mid2: srcc2 (grid B_ x 8, wave-per-row) -------------------
__global__ void __launch_bounds__(256) k_mid2(const float* __restrict__ xh0,
    const float* __restrict__ Wout, float* __restrict__ srcc2) {
  __shared__ float cat[NH_*D_];
  int b = blockIdx.x, dc = blockIdx.y;
  int t = threadIdx.x, wave = t >> 6, lane = t & 63;
  for (int n = t; n < NH_*D_; n += 256)
    cat[n] = xh0[((size_t)(n >> 8)*B_ + b)*D_ + (n & 255)];
  __syncthreads();
  for (int rr = 0; rr < 8; ++rr) {
    int d = dc*32 + wave*8 + rr;
    const float* row = Wout + (size_t)d*(NH_*D_);
    float a = 0.f;
#pragma unroll
    for (int p = 0; p < 4; ++p) {
      float4 w = *(const float4*)(row + (p*64 + lane)*4);
      float4 cv = *(const float4*)(cat + (p*64 + lane)*4);
      a += w.x*cv.x + w.y*cv.y + w.z*cv.z + w.w*cv.w;
    }
    a = wave_red(a);
    if (lane == 0) srcc2[b*D_ + d] = a;
  }
}

// ---------------- F1: x = LN(memory + srcc2) -> fp32 + bf16 -----------------
__global__ void __launch_bounds__(256) k_f1(const float* __restrict__ mem,
    const float* __restrict__ srcc2, const float* __restrict__ g,
    const float* __restrict__ bb, float* __restrict__ xf,
    unsigned short* __restrict__ xb) {
  __shared__ float red[4];
  int m = blockIdx.x, t = threadIdx.x;
  float v = mem[(size_t)m*D_ + t] + srcc2[(m & 3)*D_ + t];
  float mean = blk_sum256(v, red) * (1.f/D_);
  float d = v - mean;
  float var = blk_sum256(d*d, red) * (1.f/D_);
  float y = d * rsqrtf(var + 1e-5f) * g[t] + bb[t];
  xf[(size_t)m*D_ + t] = y;
  xb[(size_t)m*D_ + t] = f2bf(y);
}

// ---------------- F2: h1 = relu(x @ l1w^T + l1b)  bf16 (XCD-swizzled) -------
__global__ void __launch_bounds__(256) k_f2(const unsigned short* __restrict__ xb,
    const unsigned short* __restrict__ l1wb, const float* __restrict__ l1b,
    unsigned short* __restrict__ h1) {
  __shared__ __align__(16) unsigned short sm[128*LDSROW];
  int l = blockIdx.x;
  int n0 = (l & 7)*128, m0 = (l >> 3)*128;
  f32x4 acc[4][4];
#pragma unroll
  for (int i = 0; i < 4; ++i)
#pragma unroll
    for (int j = 0; j < 4; ++j) acc[i][j] = f32x4{0.f,0.f,0.f,0.f};
  gemm_kloop(xb + (size_t)m0*D_, l1wb + (size_t)n0*D_, D_, D_, D_, sm, sm + 128*64, acc);
  const int t = threadIdx.x, wave = t>>6, lane = t&63;
  const int wm = (wave>>1)*64, wn = (wave&1)*64, quad = lane>>4, c16 = lane&15;
  __syncthreads();
#pragma unroll
  for (int i = 0; i < 4; ++i)
#pragma unroll
    for (int r = 0; r < 4; ++r) {
      int mloc = wm + i*16 + quad*4 + r;
#pragma unroll
      for (int j = 0; j < 4; ++j) {
        int n = n0 + wn + j*16 + c16;
        sm[mloc*LDSROW + wn + j*16 + c16] = f2bf(fmaxf(acc[i][j][r] + l1b[n], 0.f));
      }
    }
  __syncthreads();
  const int col8 = (t & 15)*8, rsub = t >> 4;
#pragma unroll
  for (int c = 0; c < 8; ++c) {
    int mloc = c*16 + rsub;
    uint4 val = *(const uint4*)(sm + mloc*LDSROW + col8);
    *(uint4*)(h1 + (size_t)(m0 + mloc)*FF_ + n0 + col8) = val;
  }
}

// ---------------- F3: split-K 2x into two buffers (no atomics) --------------
__global__ void __launch_bounds__(256) k_f3(const unsigned short* __restrict__ h1,
    const unsigned short* __restrict__ l2wb, float* __restrict__ yfa,
    float* __restrict__ yfb) {
  __shared__ __align__(16) unsigned short smA[128*64], smB[128*64];
  int l = blockIdx.x;                 // 256 blocks: z = K-half, n (2), m (64)
  int z = l & 1, n0 = ((l >> 1) & 1)*128, m0 = (l >> 2)*128;
  float* dst = z ? yfb : yfa;
  f32x4 acc[4][4];
#pragma unroll
  for (int i = 0; i < 4; ++i)
#pragma unroll
    for (int j = 0; j < 4; ++j) acc[i][j] = f32x4{0.f,0.f,0.f,0.f};
  gemm_kloop(h1 + (size_t)m0*FF_ + z*512, l2wb + (size_t)n0*FF_ + z*512,
             FF_, FF_, 512, smA, smB, acc);
  const int t = threadIdx.x, wave = t>>6, lane = t&63;
  const int wm = (wave>>1)*64, wn = (wave&1)*64, quad = lane>>4, c16 = lane&15;
#pragma unroll
  for (int i = 0; i < 4; ++i)
#pragma unroll
    for (int r = 0; r < 4; ++r) {
      int m = m0 + wm + i*16 + quad*4 + r;
#pragma unroll
      for (int j = 0; j < 4; ++j) {
        int n = n0 + wn + j*16 + c16;
        dst[(size_t)m*D_ + n] = acc[i][j][r];
      }
    }
}

// ---------------- F4: out = LN(yfa + yfb + l2b + x) -------------------------
__global__ void __launch_bounds__(256) k_f4(const float* __restrict__ yfa,
    const float* __restrict__ yfb, const float* __restrict__ l2b,
    const float* __restrict__ xf, const float* __restrict__ g,
    const float* __restrict__ bb, float* __restrict__ out) {
  __shared__ float red[4];
  int m = blockIdx.x, t = threadIdx.x;
  size_t idx = (size_t)m*D_ + t;
  float v = yfa[idx] + yfb[idx] + l2b[t] + xf[idx];
  float mean = blk_sum256(v, red) * (1.f/D_);
  float d = v - mean;
  float var = blk_sum256(d*d, red) * (1.f/D_);
  out[idx] = d * rsqrtf(var + 1e-5f) * g[t] + bb[t];
}

// ---------------- workspace layout (bytes) ----------------------------------
constexpr size_t SZ_ACT  = (size_t)HB_*S_*K_;                   // 32 MiB (fp8)
constexpr size_t OFF_WQA = 0;
constexpr size_t OFF_WKA = OFF_WQA + SZ_ACT;
constexpr size_t OFF_KVB = OFF_WKA + SZ_ACT;                    // fp8 M*D
constexpr size_t OFF_QB  = OFF_KVB + (size_t)M_*D_;
constexpr size_t OFF_WKW = OFF_QB  + (size_t)M_*D_;             // fp8 NH*K*D
constexpr size_t OFF_WQW = OFF_WKW + (size_t)NH_*K_*D_;
constexpr size_t OFF_L1W = OFF_WQW + (size_t)NH_*K_*D_;         // bf16 FF*D
constexpr size_t OFF_L2W = OFF_L1W + (size_t)FF_*D_*2;
constexpr size_t OFF_XB  = OFF_L2W + (size_t)D_*FF_*2;          // bf16 M*D
constexpr size_t OFF_H1  = OFF_XB  + (size_t)M_*D_*2;           // bf16 M*FF
constexpr size_t OFF_XF  = OFF_H1  + (size_t)M_*FF_*2;
constexpr size_t OFF_YF0 = OFF_XF  + (size_t)M_*D_*4;
constexpr size_t OFF_YF1 = OFF_YF0 + (size_t)M_*D_*4;
constexpr size_t OFF_NQ  = OFF_YF1 + (size_t)M_*D_*4;           // zero region
constexpr size_t OFF_NK  = OFF_NQ + (size_t)HB_*S_*4;
constexpr size_t OFF_L   = OFF_NK + (size_t)HB_*S_*4;
constexpr size_t OFF_CS  = OFF_L  + (size_t)HB_*S_*4;
constexpr size_t OFF_CB  = OFF_CS + (size_t)HB_*S_*4;
constexpr size_t ZERO_BYTES = (size_t)HB_*S_*4*4 + (size_t)HB_*D_*4;
constexpr size_t OFF_P0  = OFF_CB + (size_t)HB_*D_*4;
constexpr size_t OFF_XH0 = OFF_P0 + (size_t)HB_*S_*4;
constexpr size_t OFF_SC2 = OFF_XH0 + (size_t)HB_*D_*4;
constexpr size_t OFF_RU  = OFF_SC2 + (size_t)B_*D_*4;
constexpr size_t OFF_HM  = OFF_RU  + (size_t)HB_*D_*4;
constexpr size_t OFF_S2  = OFF_HM  + (size_t)HB_*K_*4;
constexpr size_t OFF_E   = OFF_S2  + (size_t)HB_*D_*4;
constexpr size_t SZ_E    = (size_t)HB_*S_*S_;                   // 64 MiB (fp8)
constexpr size_t NEED_ALL = OFF_E + SZ_E;                       // ~185 MiB

extern "C" void kernel_launch(void* const* d_in, const int* in_sizes, int n_in,
                              void* d_out, int out_size, void* d_ws, size_t ws_size,
                              hipStream_t stream) {
  (void)in_sizes; (void)out_size;
  if (n_in < 21) return;
  const float* srcc = (const float*)d_in[0];
  const float* mem  = (const float*)d_in[1];
  const float* WK   = (const float*)d_in[2];
  const float* WQ   = (const float*)d_in[3];
  const float* WV   = (const float*)d_in[4];
  const float* Wt   = (const float*)d_in[5];
  const float* e1w  = (const float*)d_in[6];
  const float* e1b  = (const float*)d_in[7];
  const float* e2w  = (const float*)d_in[8];
  const float* e2b  = (const float*)d_in[9];
  const float* eg   = (const float*)d_in[10];
  const float* eb   = (const float*)d_in[11];
  const float* Wout = (const float*)d_in[12];
  const float* l1w  = (const float*)d_in[13];
  const float* l1b  = (const float*)d_in[14];
  const float* l2w  = (const float*)d_in[15];
  const float* l2b  = (const float*)d_in[16];
  const float* n1g  = (const float*)d_in[17];
  const float* n1b  = (const float*)d_in[18];
  const float* n3g  = (const float*)d_in[19];
  const float* n3b  = (const float*)d_in[20];

  char* ws = (char*)d_ws;
  if (ws_size < NEED_ALL) {
    fprintf(stderr, "kernel_launch: ws_size=%zu < required %zu bytes — aborting\n",
            ws_size, NEED_ALL);
    return;
  }

  unsigned char*  wqa  = (unsigned char*)(ws + OFF_WQA);
  unsigned char*  wka  = (unsigned char*)(ws + OFF_WKA);
  unsigned char*  kvb8 = (unsigned char*)(ws + OFF_KVB);
  unsigned char*  qb8  = (unsigned char*)(ws + OFF_QB);
  unsigned char*  wkw8 = (unsigned char*)(ws + OFF_WKW);
  unsigned char*  wqw8 = (unsigned char*)(ws + OFF_WQW);
  unsigned short* l1wb = (unsigned short*)(ws + OFF_L1W);
  unsigned short* l2wb = (unsigned short*)(ws + OFF_L2W);
  unsigned short* xb   = (unsigned short*)(ws + OFF_XB);
  unsigned short* h1   = (unsigned short*)(ws + OFF_H1);
  float* xf    = (float*)(ws + OFF_XF);
  float* yf0   = (float*)(ws + OFF_YF0);
  float* yf1   = (float*)(ws + OFF_YF1);
  float* nq    = (float*)(ws + OFF_NQ);
  float* nk    = (float*)(ws + OFF_NK);
  float* lrow  = (float*)(ws + OFF_L);
  float* cs    = (float*)(ws + OFF_CS);
  float* cbuf  = (float*)(ws + OFF_CB);
  float* p0    = (float*)(ws + OFF_P0);
  float* xh0   = (float*)(ws + OFF_XH0);
  float* sc2   = (float*)(ws + OFF_SC2);
  float* ruW   = (float*)(ws + OFF_RU);
  float* hmW   = (float*)(ws + OFF_HM);
  float* s2W   = (float*)(ws + OFF_S2);
  unsigned char* E = (unsigned char*)(ws + OFF_E);

  // conversions (fp8 attention inputs, bf16 FFN weights) + zero-fill
  int zfloats = (int)(ZERO_BYTES/4);
  int zblocks = (zfloats + 1023)/1024;
  k_cvtmix<<<6656 + zblocks, 256, 0, stream>>>(srcc, kvb8, mem, qb8, WK, wkw8,
                                               WQ, wqw8, l1w, l1wb, l2w, l2wb,
                                               nq, zfloats);

  // both projections (fp8 GEMM, K=256, 2 trips) + row norm^2
  k_proj2<<<4096, 256, 0, stream>>>(kvb8, wkw8, nk, wka, qb8, wqw8, nq, wqa);

  // QK^T fp8 (128x128 tile, fp8 E, hb-per-XCD locality) + weighted colsum
  k_qkA<<<4096, 256, 0, stream>>>(wqa, wka, nq, nk, lrow, E);
  k_colsumE<<<dim3(HB_, 16), 256, 0, stream>>>(E, lrow, cs, p0);

  // q=0 tail of the RMA block
  k_mid0<<<dim3(HB_, S_/128), 256, 0, stream>>>(p0, cs, srcc, cbuf);
  k_mid1a<<<HB_, 256, 0, stream>>>(cbuf, mem, WV, Wt, ruW);
  k_mid1b<<<dim3(HB_, 8), 256, 0, stream>>>(ruW, e1w, e1b, hmW);
  k_mid1c<<<dim3(HB_, 8), 256, 0, stream>>>(hmW, e2w, e2b, s2W);
  k_mid1d<<<HB_, 256, 0, stream>>>(ruW, s2W, eg, eb, xh0);
  k_mid2<<<dim3(B_, 8), 256, 0, stream>>>(xh0, Wout, sc2);

  // decoder FFN (bf16 GEMMs — fp8 here exceeded the accuracy budget, r11)
  k_f1<<<M_, 256, 0, stream>>>(mem, sc2, n1g, n1b, xf, xb);
  k_f2<<<512, 256, 0, stream>>>(xb, l1wb, l1b, h1);
  k_f3<<<256, 256, 0, stream>>>(h1, l2wb, yf0, yf1);
  k_f4<<<M_, 256, 0, stream>>>(yf0, yf1, l2b, xf, n3g, n3b, (float*)d_out);
}